// Round 13
// baseline (787.158 us; speedup 1.0000x reference)
//
#include <hip/hip_runtime.h>

// GIN encoder w/ virtual node, 3 layers, H=128. Round 13 (base: round 12, 783us):
// drop layer-1 f32 out_feats write (dead: overwritten by layer 2); pool from
// bf16 fb2; nontemporal z store in aggregate (L2-pollution probe).

#define HDIM 128
#define H2DIM 256
#define GNUM 512
#define BN_EPS 1e-5f

typedef short bf16x8 __attribute__((ext_vector_type(8)));
typedef float f32x4 __attribute__((ext_vector_type(4)));
typedef unsigned int u32x4 __attribute__((ext_vector_type(4)));

__device__ __forceinline__ unsigned short f2bf(float f) {
  unsigned int u = __float_as_uint(f);
  u = (u + 0x7FFFu + ((u >> 16) & 1u)) >> 16;
  return (unsigned short)u;
}
__device__ __forceinline__ float bf2f(unsigned short s) {
  return __uint_as_float(((unsigned int)s) << 16);
}

// ---------------- elementwise / init ----------------

__global__ __launch_bounds__(256) void k_init_vf(const float* __restrict__ emb,
                                                 float* __restrict__ vf) {
  int idx = blockIdx.x * 256 + threadIdx.x;
  if (idx < GNUM * HDIM) vf[idx] = emb[idx & (HDIM - 1)];
}

// h(bf16) = feats(f32) (layer 0, no vf)
__global__ __launch_bounds__(256) void k_h_init(const float* __restrict__ feats,
                                                unsigned short* __restrict__ h,
                                                int N) {
  int idx = blockIdx.x * 256 + threadIdx.x;
  int total = N * (HDIM / 4);
  if (idx >= total) return;
  float4 v = ((const float4*)feats)[idx];
  ushort4 o;
  o.x = f2bf(v.x); o.y = f2bf(v.y); o.z = f2bf(v.z); o.w = f2bf(v.w);
  ((ushort4*)h)[idx] = o;
}

// h(bf16) = feats_b(bf16) + vf[batch]  (layer 2)
__global__ __launch_bounds__(256) void k_h_init_b(const unsigned short* __restrict__ fb,
                                                  const float* __restrict__ vf,
                                                  const int* __restrict__ batch,
                                                  unsigned short* __restrict__ h,
                                                  int N) {
  int idx = blockIdx.x * 256 + threadIdx.x;
  int total = N * (HDIM / 4);
  if (idx >= total) return;
  int n = idx >> 5;
  int c4 = idx & 31;
  ushort4 u = ((const ushort4*)fb)[idx];
  int g = batch[n];
  float4 w = ((const float4*)(vf + (size_t)g * HDIM))[c4];
  ushort4 o;
  o.x = f2bf(bf2f(u.x) + w.x);
  o.y = f2bf(bf2f(u.y) + w.y);
  o.z = f2bf(bf2f(u.z) + w.z);
  o.w = f2bf(bf2f(u.w) + w.w);
  ((ushort4*)h)[idx] = o;
}

// layer-0 epilogue: h(bf16) = relu(bn(y2 bf16)) + vf[batch]
__global__ __launch_bounds__(256) void k_bnfuse_b(const unsigned short* __restrict__ Y,
                                                  const float* __restrict__ scale,
                                                  const float* __restrict__ shift,
                                                  const float* __restrict__ vf,
                                                  const int* __restrict__ batch,
                                                  unsigned short* __restrict__ hout,
                                                  int N) {
  int idx = blockIdx.x * 256 + threadIdx.x;
  int total = N * (HDIM / 4);
  if (idx >= total) return;
  int n = idx >> 5;
  int c4 = idx & 31;
  int c = c4 * 4;
  ushort4 u = ((const ushort4*)Y)[idx];
  int g = batch[n];
  float4 w = ((const float4*)(vf + (size_t)g * HDIM))[c4];
  float vx = fmaxf(fmaf(bf2f(u.x), scale[c + 0], shift[c + 0]), 0.f) + w.x;
  float vy = fmaxf(fmaf(bf2f(u.y), scale[c + 1], shift[c + 1]), 0.f) + w.y;
  float vz = fmaxf(fmaf(bf2f(u.z), scale[c + 2], shift[c + 2]), 0.f) + w.z;
  float vw = fmaxf(fmaf(bf2f(u.w), scale[c + 3], shift[c + 3]), 0.f) + w.w;
  ushort4 o;
  o.x = f2bf(vx); o.y = f2bf(vy); o.z = f2bf(vz); o.w = f2bf(vw);
  ((ushort4*)hout)[idx] = o;
}

// layer-1 epilogue: fb2(bf16) = relu(bn(y2 bf16))  (no f32 write; dead output)
__global__ __launch_bounds__(256) void k_bnapply_b1(
    const unsigned short* __restrict__ Y, const float* __restrict__ scale,
    const float* __restrict__ shift, unsigned short* __restrict__ outb, int N) {
  int idx = blockIdx.x * 256 + threadIdx.x;
  int total = N * (HDIM / 4);
  if (idx >= total) return;
  int c = (idx & 31) * 4;
  ushort4 u = ((const ushort4*)Y)[idx];
  ushort4 o;
  o.x = f2bf(fmaxf(fmaf(bf2f(u.x), scale[c + 0], shift[c + 0]), 0.f));
  o.y = f2bf(fmaxf(fmaf(bf2f(u.y), scale[c + 1], shift[c + 1]), 0.f));
  o.z = f2bf(fmaxf(fmaf(bf2f(u.z), scale[c + 2], shift[c + 2]), 0.f));
  o.w = f2bf(fmaxf(fmaf(bf2f(u.w), scale[c + 3], shift[c + 3]), 0.f));
  ((ushort4*)outb)[idx] = o;
}

// layer-2 epilogue: out(f32) = bn(y2 f32), no relu
__global__ __launch_bounds__(256) void k_bnapply(const float* __restrict__ Y,
                                                 const float* __restrict__ scale,
                                                 const float* __restrict__ shift,
                                                 float* __restrict__ out,
                                                 long long total4, int Cq, int relu) {
  long long idx = (long long)blockIdx.x * 256 + threadIdx.x;
  if (idx >= total4) return;
  int c = (int)(idx % Cq) * 4;
  float4 v = ((const float4*)Y)[idx];
  v.x = fmaf(v.x, scale[c + 0], shift[c + 0]);
  v.y = fmaf(v.y, scale[c + 1], shift[c + 1]);
  v.z = fmaf(v.z, scale[c + 2], shift[c + 2]);
  v.w = fmaf(v.w, scale[c + 3], shift[c + 3]);
  if (relu) {
    v.x = fmaxf(v.x, 0.f); v.y = fmaxf(v.y, 0.f);
    v.z = fmaxf(v.z, 0.f); v.w = fmaxf(v.w, 0.f);
  }
  ((float4*)out)[idx] = v;
}

__global__ __launch_bounds__(256) void k_convw_all(const float* __restrict__ w1,
                                                   const float* __restrict__ w2,
                                                   unsigned short* __restrict__ wt1,
                                                   unsigned short* __restrict__ wt2) {
  int idx = blockIdx.x * 256 + threadIdx.x;
  const int P = 3 * HDIM * H2DIM;
  if (idx < P) {
    int i = idx / (H2DIM * HDIM);
    int o = idx % (H2DIM * HDIM);
    int n = o / HDIM;
    int k = o % HDIM;
    wt1[idx] = f2bf(w1[(size_t)i * HDIM * H2DIM + (size_t)k * H2DIM + n]);
  } else if (idx < 2 * P) {
    int o2 = idx - P;
    int i = o2 / (HDIM * H2DIM);
    int o = o2 % (HDIM * H2DIM);
    int n = o / H2DIM;
    int k = o % H2DIM;
    wt2[o2] = f2bf(w2[(size_t)i * H2DIM * HDIM + (size_t)k * HDIM + n]);
  }
}

// ---------------- CSR build ----------------

__global__ __launch_bounds__(256) void k_hist(const int* __restrict__ ei,
                                              int* __restrict__ deg, int E) {
  int e = blockIdx.x * 256 + threadIdx.x;
  if (e < E) atomicAdd(&deg[ei[E + e]], 1);
}

__global__ __launch_bounds__(256) void k_scan1(const int* __restrict__ deg,
                                               int* __restrict__ bsum, int N) {
  __shared__ int sh[256];
  int t = threadIdx.x;
  int base = blockIdx.x * 2048 + t * 8;
  int s = 0;
#pragma unroll
  for (int j = 0; j < 8; ++j) {
    int i = base + j;
    if (i < N) s += deg[i];
  }
  sh[t] = s;
  __syncthreads();
  for (int off = 128; off > 0; off >>= 1) {
    if (t < off) sh[t] += sh[t + off];
    __syncthreads();
  }
  if (t == 0) bsum[blockIdx.x] = sh[0];
}

__global__ __launch_bounds__(256) void k_scan2(int* __restrict__ bsum, int nb,
                                               int* __restrict__ row_ptr, int N) {
  __shared__ int sh[256];
  int t = threadIdx.x;
  int v = (t < nb) ? bsum[t] : 0;
  sh[t] = v;
  __syncthreads();
  for (int off = 1; off < 256; off <<= 1) {
    int add = (t >= off) ? sh[t - off] : 0;
    __syncthreads();
    sh[t] += add;
    __syncthreads();
  }
  if (t < nb) bsum[t] = sh[t] - v;
  if (t == 255) row_ptr[N] = sh[255];
}

__global__ __launch_bounds__(256) void k_scan3(const int* __restrict__ deg,
                                               const int* __restrict__ boff,
                                               int* __restrict__ row_ptr, int N) {
  __shared__ int sh[256];
  int t = threadIdx.x;
  int base = blockIdx.x * 2048 + t * 8;
  int d[8];
  int s = 0;
#pragma unroll
  for (int j = 0; j < 8; ++j) {
    int i = base + j;
    d[j] = (i < N) ? deg[i] : 0;
    s += d[j];
  }
  sh[t] = s;
  __syncthreads();
  for (int off = 1; off < 256; off <<= 1) {
    int add = (t >= off) ? sh[t - off] : 0;
    __syncthreads();
    sh[t] += add;
    __syncthreads();
  }
  int run = boff[blockIdx.x] + sh[t] - s;
#pragma unroll
  for (int j = 0; j < 8; ++j) {
    int i = base + j;
    if (i < N) {
      row_ptr[i] = run;
      run += d[j];
    }
  }
}

__global__ __launch_bounds__(256) void k_binA(const int* __restrict__ ei,
                                              const int* __restrict__ row_ptr,
                                              int* __restrict__ bktcur,
                                              int* __restrict__ staged,
                                              int E, int NB) {
  __shared__ int hist[512];
  __shared__ int lbase[512];
  int tid = threadIdx.x;
  hist[tid] = 0; hist[tid + 256] = 0;
  __syncthreads();
  int e0 = blockIdx.x * 4096;
#pragma unroll
  for (int j = 0; j < 16; ++j) {
    int e = e0 + j * 256 + tid;
    if (e < E) atomicAdd(&hist[ei[E + e] >> 8], 1);
  }
  __syncthreads();
  for (int t = tid; t < NB; t += 256) {
    int cgot = hist[t];
    if (cgot > 0) lbase[t] = row_ptr[t << 8] + atomicAdd(&bktcur[t], cgot);
    hist[t] = 0;
  }
  __syncthreads();
#pragma unroll
  for (int j = 0; j < 16; ++j) {
    int e = e0 + j * 256 + tid;
    if (e < E) {
      int d = ei[E + e];
      int b = d >> 8;
      int loc = atomicAdd(&hist[b], 1);
      staged[lbase[b] + loc] = (ei[e] << 8) | (d & 255);
    }
  }
}

__global__ __launch_bounds__(256) void k_binB(const int* __restrict__ row_ptr,
                                              const int* __restrict__ staged,
                                              int* __restrict__ csr, int N) {
  __shared__ int lcur[256];
  int b = blockIdx.x;
  int node0 = b << 8;
  int tid = threadIdx.x;
  int nend = min(node0 + 256, N);
  lcur[tid] = (node0 + tid < N) ? row_ptr[node0 + tid] : 0;
  __syncthreads();
  int s0 = row_ptr[node0];
  int s1 = row_ptr[nend];
  for (int j = s0 + tid; j < s1; j += 256) {
    int rec = staged[j];
    int pos = atomicAdd(&lcur[rec & 255], 1);
    csr[pos] = rec >> 8;
  }
}

// ---------------- aggregation (bf16) ----------------
__device__ __forceinline__ void acc8(float* a, uint4 v) {
  a[0] += bf2f((unsigned short)v.x); a[1] += bf2f((unsigned short)(v.x >> 16));
  a[2] += bf2f((unsigned short)v.y); a[3] += bf2f((unsigned short)(v.y >> 16));
  a[4] += bf2f((unsigned short)v.z); a[5] += bf2f((unsigned short)(v.z >> 16));
  a[6] += bf2f((unsigned short)v.w); a[7] += bf2f((unsigned short)(v.w >> 16));
}

__global__ __launch_bounds__(256) void k_aggregate(const unsigned short* __restrict__ h,
                                                   const int* __restrict__ row_ptr,
                                                   const int* __restrict__ csr,
                                                   unsigned short* __restrict__ z,
                                                   int N) {
  int n = blockIdx.x * 16 + (threadIdx.x >> 4);
  if (n >= N) return;
  int lane = threadIdx.x & 15;
  const uint4* __restrict__ hp = (const uint4*)h;
  float a[8];
  {
    uint4 u = hp[(size_t)n * 16 + lane];
    a[0] = bf2f((unsigned short)u.x); a[1] = bf2f((unsigned short)(u.x >> 16));
    a[2] = bf2f((unsigned short)u.y); a[3] = bf2f((unsigned short)(u.y >> 16));
    a[4] = bf2f((unsigned short)u.z); a[5] = bf2f((unsigned short)(u.z >> 16));
    a[6] = bf2f((unsigned short)u.w); a[7] = bf2f((unsigned short)(u.w >> 16));
  }
  int beg = row_ptr[n], end = row_ptr[n + 1];
  int j = beg;
  for (; j + 4 <= end; j += 4) {
    int s0 = csr[j], s1 = csr[j + 1], s2 = csr[j + 2], s3 = csr[j + 3];
    uint4 v0 = hp[(size_t)s0 * 16 + lane];
    uint4 v1 = hp[(size_t)s1 * 16 + lane];
    uint4 v2 = hp[(size_t)s2 * 16 + lane];
    uint4 v3 = hp[(size_t)s3 * 16 + lane];
    acc8(a, v0); acc8(a, v1); acc8(a, v2); acc8(a, v3);
  }
  for (; j < end; ++j) {
    uint4 v = hp[(size_t)csr[j] * 16 + lane];
    acc8(a, v);
  }
  u32x4 o;
  o.x = (unsigned int)f2bf(a[0]) | ((unsigned int)f2bf(a[1]) << 16);
  o.y = (unsigned int)f2bf(a[2]) | ((unsigned int)f2bf(a[3]) << 16);
  o.z = (unsigned int)f2bf(a[4]) | ((unsigned int)f2bf(a[5]) << 16);
  o.w = (unsigned int)f2bf(a[6]) | ((unsigned int)f2bf(a[7]) << 16);
  // nontemporal: don't let the z stream evict hot h lines from L2
  __builtin_nontemporal_store(o, (u32x4*)z + (size_t)n * 16 + lane);
}

// ---------------- MFMA GEMM: 64x128 tile, BK=64, partial-buffer stats --------
#define LDA_S 76
__global__ __launch_bounds__(256) void k_gemm_mfma(
    const unsigned short* __restrict__ A, const unsigned short* __restrict__ Wt,
    const float* __restrict__ bias, const float* __restrict__ kscale,
    const float* __restrict__ kshift, void* __restrict__ Cout, int outBf16,
    float* __restrict__ pS, float* __restrict__ pQ, int mblocks,
    int M, int K, int Nc) {
  __shared__ unsigned short As[64 * LDA_S];
  __shared__ unsigned short Bs[128 * LDA_S];
  __shared__ float redS[128];
  __shared__ float redQ[128];
  __shared__ float ksc[256];
  __shared__ float ksh[256];

  int tid = threadIdx.x;
  int lane = tid & 63;
  int wid = tid >> 6;
  int wrow = (wid & 1) * 32;
  int wcol = (wid >> 1) * 64;
  int bm = blockIdx.x * 64;
  int bn = blockIdx.y * 128;
  int lrow = lane & 15;
  int lkg = lane >> 4;

  if (tid < 128) { redS[tid] = 0.f; redQ[tid] = 0.f; }
  if (kscale) {
    for (int k = tid; k < K; k += 256) { ksc[k] = kscale[k]; ksh[k] = kshift[k]; }
  }

  f32x4 acc[2][4];
#pragma unroll
  for (int r = 0; r < 2; ++r)
#pragma unroll
    for (int c = 0; c < 4; ++c) acc[r][c] = (f32x4){0.f, 0.f, 0.f, 0.f};

  for (int kt = 0; kt < K; kt += 64) {
    __syncthreads();
#pragma unroll
    for (int it = 0; it < 2; ++it) {
      int ga = it * 256 + tid;
      int row = ga >> 3;
      int g = ga & 7;
      int k0 = kt + g * 8;
      bf16x8 av = (bf16x8){0, 0, 0, 0, 0, 0, 0, 0};
      int grow = bm + row;
      if (grow < M) av = *(const bf16x8*)(A + (size_t)grow * K + k0);
      if (kscale) {
#pragma unroll
        for (int j = 0; j < 8; ++j) {
          float f = bf2f((unsigned short)av[j]);
          f = fmaxf(fmaf(f, ksc[k0 + j], ksh[k0 + j]), 0.f);
          av[j] = (short)f2bf(f);
        }
      }
      *(bf16x8*)(As + row * LDA_S + g * 8) = av;
    }
#pragma unroll
    for (int it = 0; it < 4; ++it) {
      int gb = it * 256 + tid;
      int row = gb >> 3;
      int g = gb & 7;
      bf16x8 bv = *(const bf16x8*)(Wt + (size_t)(bn + row) * K + kt + g * 8);
      *(bf16x8*)(Bs + row * LDA_S + g * 8) = bv;
    }
    __syncthreads();
#pragma unroll
    for (int ks = 0; ks < 2; ++ks) {
      int goff = ks * 4 + lkg;
      bf16x8 af[2], bfr[4];
#pragma unroll
      for (int rf = 0; rf < 2; ++rf)
        af[rf] = *(const bf16x8*)(As + (wrow + rf * 16 + lrow) * LDA_S + goff * 8);
#pragma unroll
      for (int cf = 0; cf < 4; ++cf)
        bfr[cf] = *(const bf16x8*)(Bs + (wcol + cf * 16 + lrow) * LDA_S + goff * 8);
#pragma unroll
      for (int rf = 0; rf < 2; ++rf)
#pragma unroll
        for (int cf = 0; cf < 4; ++cf)
          acc[rf][cf] = __builtin_amdgcn_mfma_f32_16x16x32_bf16(
              af[rf], bfr[cf], acc[rf][cf], 0, 0, 0);
    }
  }

#pragma unroll
  for (int cf = 0; cf < 4; ++cf) {
    int lcol = wcol + cf * 16 + lrow;
    float bb = bias[bn + lcol];
    float s = 0.f, q = 0.f;
#pragma unroll
    for (int rf = 0; rf < 2; ++rf) {
#pragma unroll
      for (int j = 0; j < 4; ++j) {
        float v = acc[rf][cf][j] + bb;
        acc[rf][cf][j] = v;
        int grow = bm + wrow + rf * 16 + lkg * 4 + j;
        if (grow < M) { s += v; q += v * v; }
      }
    }
    s += __shfl_xor(s, 16); s += __shfl_xor(s, 32);
    q += __shfl_xor(q, 16); q += __shfl_xor(q, 32);
    if (lane < 16) {
      atomicAdd(&redS[lcol], s);
      atomicAdd(&redQ[lcol], q);
    }
  }

#pragma unroll
  for (int cf = 0; cf < 4; ++cf) {
    int col = bn + wcol + cf * 16 + lrow;
#pragma unroll
    for (int rf = 0; rf < 2; ++rf) {
#pragma unroll
      for (int j = 0; j < 4; ++j) {
        int grow = bm + wrow + rf * 16 + lkg * 4 + j;
        if (grow < M) {
          float v = acc[rf][cf][j];
          if (outBf16)
            ((unsigned short*)Cout)[(size_t)grow * Nc + col] = f2bf(v);
          else
            ((float*)Cout)[(size_t)grow * Nc + col] = v;
        }
      }
    }
  }
  __syncthreads();
  if (tid < 128) {
    size_t off = (size_t)(bn + tid) * mblocks + blockIdx.x;
    pS[off] = redS[tid];
    pQ[off] = redQ[tid];
  }
}

__global__ __launch_bounds__(256) void k_bnfin2(const float* __restrict__ pS,
                                                const float* __restrict__ pQ,
                                                const float* __restrict__ g,
                                                const float* __restrict__ b,
                                                float* __restrict__ scale,
                                                float* __restrict__ shift,
                                                int mblocks, float invM) {
  __shared__ float shS[256], shQ[256];
  int c = blockIdx.x;
  int t = threadIdx.x;
  const float* rs = pS + (size_t)c * mblocks;
  const float* rq = pQ + (size_t)c * mblocks;
  float s = 0.f, q = 0.f;
  for (int j = t; j < mblocks; j += 256) { s += rs[j]; q += rq[j]; }
  shS[t] = s; shQ[t] = q;
  __syncthreads();
  for (int off = 128; off > 0; off >>= 1) {
    if (t < off) { shS[t] += shS[t + off]; shQ[t] += shQ[t + off]; }
    __syncthreads();
  }
  if (t == 0) {
    float mean = shS[0] * invM;
    float var = shQ[0] * invM - mean * mean;
    float inv = rsqrtf(var + BN_EPS);
    float sc = g[c] * inv;
    scale[c] = sc;
    shift[c] = fmaf(-mean, sc, b[c]);
  }
}

// ---------------- GEMM 64x64 f32 (vn-MLP, 512 rows) ----------------
__global__ __launch_bounds__(256) void k_gemm(const float* __restrict__ A,
                                              const float* __restrict__ B,
                                              const float* __restrict__ bias,
                                              const float* __restrict__ kscale,
                                              const float* __restrict__ kshift,
                                              float* __restrict__ C,
                                              int M, int K, int Nc) {
  __shared__ float As[16][65];
  __shared__ float Bs[16][65];
  int tid = threadIdx.x;
  int bm = blockIdx.x * 64;
  int bn = blockIdx.y * 64;
  int trow = (tid >> 4) << 2;
  int tcol = (tid & 15) << 2;
  float acc[4][4] = {};

  int arow = tid >> 2;
  int ak = (tid & 3) << 2;
  int bt4 = tid << 2;
  int bk = bt4 >> 6;
  int bcol = bt4 & 63;

  for (int kt = 0; kt < K; kt += 16) {
    float4 av = make_float4(0.f, 0.f, 0.f, 0.f);
    int grow = bm + arow;
    if (grow < M) av = *(const float4*)(A + (size_t)grow * K + kt + ak);
    if (kscale) {
      int k0 = kt + ak;
      av.x = fmaxf(fmaf(av.x, kscale[k0 + 0], kshift[k0 + 0]), 0.f);
      av.y = fmaxf(fmaf(av.y, kscale[k0 + 1], kshift[k0 + 1]), 0.f);
      av.z = fmaxf(fmaf(av.z, kscale[k0 + 2], kshift[k0 + 2]), 0.f);
      av.w = fmaxf(fmaf(av.w, kscale[k0 + 3], kshift[k0 + 3]), 0.f);
    }
    float4 bv = *(const float4*)(B + (size_t)(kt + bk) * Nc + bn + bcol);
    __syncthreads();
    As[ak + 0][arow] = av.x;
    As[ak + 1][arow] = av.y;
    As[ak + 2][arow] = av.z;
    As[ak + 3][arow] = av.w;
    Bs[bk][bcol + 0] = bv.x;
    Bs[bk][bcol + 1] = bv.y;
    Bs[bk][bcol + 2] = bv.z;
    Bs[bk][bcol + 3] = bv.w;
    __syncthreads();
#pragma unroll
    for (int k = 0; k < 16; ++k) {
      float a0 = As[k][trow + 0], a1 = As[k][trow + 1];
      float a2 = As[k][trow + 2], a3 = As[k][trow + 3];
      float b0 = Bs[k][tcol + 0], b1 = Bs[k][tcol + 1];
      float b2 = Bs[k][tcol + 2], b3 = Bs[k][tcol + 3];
      acc[0][0] = fmaf(a0, b0, acc[0][0]); acc[0][1] = fmaf(a0, b1, acc[0][1]);
      acc[0][2] = fmaf(a0, b2, acc[0][2]); acc[0][3] = fmaf(a0, b3, acc[0][3]);
      acc[1][0] = fmaf(a1, b0, acc[1][0]); acc[1][1] = fmaf(a1, b1, acc[1][1]);
      acc[1][2] = fmaf(a1, b2, acc[1][2]); acc[1][3] = fmaf(a1, b3, acc[1][3]);
      acc[2][0] = fmaf(a2, b0, acc[2][0]); acc[2][1] = fmaf(a2, b1, acc[2][1]);
      acc[2][2] = fmaf(a2, b2, acc[2][2]); acc[2][3] = fmaf(a2, b3, acc[2][3]);
      acc[3][0] = fmaf(a3, b0, acc[3][0]); acc[3][1] = fmaf(a3, b1, acc[3][1]);
      acc[3][2] = fmaf(a3, b2, acc[3][2]); acc[3][3] = fmaf(a3, b3, acc[3][3]);
    }
  }
#pragma unroll
  for (int r = 0; r < 4; ++r) {
    int grow = bm + trow + r;
    if (grow < M) {
      float4 o;
      o.x = acc[r][0] + bias[bn + tcol + 0];
      o.y = acc[r][1] + bias[bn + tcol + 1];
      o.z = acc[r][2] + bias[bn + tcol + 2];
      o.w = acc[r][3] + bias[bn + tcol + 3];
      *(float4*)(C + (size_t)grow * Nc + bn + tcol) = o;
    }
  }
}

// ---------------- BN stats / finalize (vn-MLP path) ----------------

__global__ void k_colstats(const float* __restrict__ Y, int M, int C, int stripe,
                           float* __restrict__ sum, float* __restrict__ sumsq) {
  int c = threadIdx.x;
  int r0 = blockIdx.x * stripe;
  int r1 = min(r0 + stripe, M);
  float s = 0.f, ss = 0.f;
  for (int r = r0; r < r1; ++r) {
    float v = Y[(size_t)r * C + c];
    s += v; ss += v * v;
  }
  atomicAdd(&sum[c], s);
  atomicAdd(&sumsq[c], ss);
}

__global__ void k_bnfin(const float* __restrict__ sum, const float* __restrict__ sumsq,
                        const float* __restrict__ g, const float* __restrict__ b,
                        float* __restrict__ scale, float* __restrict__ shift,
                        int C, float invM) {
  int c = threadIdx.x;
  if (c >= C) return;
  float mean = sum[c] * invM;
  float var = sumsq[c] * invM - mean * mean;
  float inv = rsqrtf(var + BN_EPS);
  float sc = g[c] * inv;
  scale[c] = sc;
  shift[c] = fmaf(-mean, sc, b[c]);
}

// ---------------- pooling / readout / small ops ----------------

// f32-input segment pooling (sorted batch), counts fused
__global__ __launch_bounds__(256) void k_pool2(const float* __restrict__ X,
                                               const int* __restrict__ batch,
                                               float* __restrict__ pooled,
                                               float* __restrict__ counts, int N) {
  int c = threadIdx.x & 127;
  int half = threadIdx.x >> 7;
  int base = blockIdx.x * 128 + half * 64;
  if (base >= N) return;
  int lim = min(64, N - base);
  int g = batch[base];
  float acc = 0.f, cnt = 0.f;
  for (int r = 0; r < lim; ++r) {
    int bg = batch[base + r];
    if (bg != g) {
      atomicAdd(&pooled[(size_t)g * HDIM + c], acc);
      if (c == 0 && counts) atomicAdd(&counts[g], cnt);
      acc = 0.f; cnt = 0.f; g = bg;
    }
    acc += X[(size_t)(base + r) * HDIM + c];
    cnt += 1.f;
  }
  atomicAdd(&pooled[(size_t)g * HDIM + c], acc);
  if (c == 0 && counts) atomicAdd(&counts[g], cnt);
}

// bf16-input variant (layer-1 vn pooling reads fb2)
__global__ __launch_bounds__(256) void k_pool2_b(const unsigned short* __restrict__ X,
                                                 const int* __restrict__ batch,
                                                 float* __restrict__ pooled, int N) {
  int c = threadIdx.x & 127;
  int half = threadIdx.x >> 7;
  int base = blockIdx.x * 128 + half * 64;
  if (base >= N) return;
  int lim = min(64, N - base);
  int g = batch[base];
  float acc = 0.f;
  for (int r = 0; r < lim; ++r) {
    int bg = batch[base + r];
    if (bg != g) {
      atomicAdd(&pooled[(size_t)g * HDIM + c], acc);
      acc = 0.f; g = bg;
    }
    acc += bf2f(X[(size_t)(base + r) * HDIM + c]);
  }
  atomicAdd(&pooled[(size_t)g * HDIM + c], acc);
}

__global__ __launch_bounds__(256) void k_add(const float* __restrict__ a,
                                             const float* __restrict__ b,
                                             float* __restrict__ o, int n) {
  int idx = blockIdx.x * 256 + threadIdx.x;
  if (idx < n) o[idx] = a[idx] + b[idx];
}

__global__ __launch_bounds__(256) void k_readout(const float* __restrict__ pooled,
                                                 const float* __restrict__ counts,
                                                 float* __restrict__ out, int n) {
  int idx = blockIdx.x * 256 + threadIdx.x;
  if (idx >= n) return;
  int g = idx >> 7;
  out[idx] = pooled[idx] / fmaxf(counts[g], 1.0f);
}

// ---------------- launch ----------------

extern "C" void kernel_launch(void* const* d_in, const int* in_sizes, int n_in,
                              void* d_out, int out_size, void* d_ws, size_t ws_size,
                              hipStream_t stream) {
  const float* x       = (const float*)d_in[0];
  const int*   ei      = (const int*)d_in[1];
  const int*   batch   = (const int*)d_in[2];
  const float* conv_w1 = (const float*)d_in[4];
  const float* conv_b1 = (const float*)d_in[5];
  const float* conv_bng = (const float*)d_in[6];
  const float* conv_bnb = (const float*)d_in[7];
  const float* conv_w2 = (const float*)d_in[8];
  const float* conv_b2 = (const float*)d_in[9];
  const float* bn_g    = (const float*)d_in[10];
  const float* bn_b    = (const float*)d_in[11];
  const float* vn_emb  = (const float*)d_in[12];
  const float* vw1     = (const float*)d_in[13];
  const float* vb1     = (const float*)d_in[14];
  const float* vbn1g   = (const float*)d_in[15];
  const float* vbn1b   = (const float*)d_in[16];
  const float* vw2     = (const float*)d_in[17];
  const float* vb2     = (const float*)d_in[18];
  const float* vbn2g   = (const float*)d_in[19];
  const float* vbn2b   = (const float*)d_in[20];

  const int N = in_sizes[2];
  const int E = in_sizes[1] / 2;
  const int L = 3;

  const size_t NH  = (size_t)N * HDIM;
  const size_t NH2 = (size_t)N * H2DIM;

  float*          y2   = (float*)d_ws;
  unsigned short* h_b  = (unsigned short*)d_ws;
  unsigned short* z_b  = h_b + NH;            // also y2b (bf16 y2, layers 0/1)
  unsigned short* y1_b = z_b + NH;
  unsigned short* wt1b = y1_b + NH2;
  unsigned short* wt2b = wt1b + (size_t)3 * H2DIM * HDIM;
  float* sum1   = (float*)(wt2b + (size_t)3 * HDIM * H2DIM);
  float* ss1    = sum1 + H2DIM;
  float* sum2   = ss1 + H2DIM;
  float* ss2    = sum2 + HDIM;
  float* scale1 = ss2 + HDIM;
  float* shift1 = scale1 + H2DIM;
  float* scale2 = shift1 + H2DIM;
  float* shift2 = scale2 + HDIM;
  float* vf     = shift2 + HDIM;
  float* pooled = vf + (size_t)GNUM * HDIM;
  float* vin    = pooled + (size_t)GNUM * HDIM;
  float* v1     = vin + (size_t)GNUM * HDIM;
  float* counts = v1 + (size_t)GNUM * H2DIM;
  int*   cursor = (int*)(counts + GNUM);
  int*   bktcur = cursor + N;
  int*   row_ptr = bktcur + 512;
  int*   csr    = row_ptr + N + 1;
  int*   staged = csr + E;
  int*   bsum   = staged + E;
  unsigned short* hb2 = (unsigned short*)(bsum + 256);
  unsigned short* fb2 = hb2 + NH;             // bf16 feats copy (layer-1 out)

  const int mblocks = (N + 63) / 64;
  float* pS = (float*)staged;   // reuse: dead after CSR build
  float* pQ = pS + (size_t)256 * mblocks;

  float* out_feats = (float*)d_out;
  float* out_read  = out_feats + NH;
  float* out_vf    = out_read + (size_t)GNUM * HDIM;

  dim3 blk(256);
  const int gridNH4 = (int)((NH / 4 + 255) / 256);
  const int gridE = (E + 255) / 256;
  const int nb = (N + 2047) / 2048;
  const int NB = (N + 255) >> 8;

  // ---- CSR build ----
  hipMemsetAsync(cursor, 0, (size_t)(N + 512) * sizeof(int), stream);
  k_hist<<<gridE, blk, 0, stream>>>(ei, cursor, E);
  k_scan1<<<nb, blk, 0, stream>>>(cursor, bsum, N);
  k_scan2<<<1, blk, 0, stream>>>(bsum, nb, row_ptr, N);
  k_scan3<<<nb, blk, 0, stream>>>(cursor, bsum, row_ptr, N);
  k_binA<<<(E + 4095) / 4096, blk, 0, stream>>>(ei, row_ptr, bktcur, staged, E, NB);
  k_binB<<<NB, blk, 0, stream>>>(row_ptr, staged, csr, N);

  // ---- weight conversion ----
  k_convw_all<<<(2 * 3 * HDIM * H2DIM + 255) / 256, blk, 0, stream>>>(
      conv_w1, conv_w2, wt1b, wt2b);

  k_init_vf<<<(GNUM * HDIM + 255) / 256, blk, 0, stream>>>(vn_emb, vf);

  for (int i = 0; i < L; ++i) {
    if (i == 0)
      k_h_init<<<gridNH4, blk, 0, stream>>>(x, h_b, N);
    else if (i == 2)
      k_h_init_b<<<gridNH4, blk, 0, stream>>>(fb2, vf, batch, h_b, N);
    const unsigned short* hcur = (i == 1) ? hb2 : h_b;

    k_aggregate<<<(N + 15) / 16, blk, 0, stream>>>(hcur, row_ptr, csr, z_b, N);

    // GEMM1: y1_b(bf16) = z_b @ W1[i] + b1[i], partial-buffer stats
    k_gemm_mfma<<<dim3(mblocks, H2DIM / 128), blk, 0, stream>>>(
        z_b, wt1b + (size_t)i * H2DIM * HDIM, conv_b1 + (size_t)i * H2DIM,
        nullptr, nullptr, y1_b, 1, pS, pQ, mblocks, N, HDIM, H2DIM);
    k_bnfin2<<<H2DIM, blk, 0, stream>>>(pS, pQ, conv_bng + (size_t)i * H2DIM,
                                        conv_bnb + (size_t)i * H2DIM,
                                        scale1, shift1, mblocks, 1.0f / N);

    // GEMM2: y2 = relu(bn(y1)) @ W2[i] + b2[i]; bf16 output into z_b for i<2
    int outBf = (i < 2) ? 1 : 0;
    void* y2dst = (i < 2) ? (void*)z_b : (void*)y2;
    k_gemm_mfma<<<dim3(mblocks, HDIM / 128), blk, 0, stream>>>(
        y1_b, wt2b + (size_t)i * HDIM * H2DIM, conv_b2 + (size_t)i * HDIM,
        scale1, shift1, y2dst, outBf, pS, pQ, mblocks, N, H2DIM, HDIM);
    k_bnfin2<<<HDIM, blk, 0, stream>>>(pS, pQ, bn_g + (size_t)i * HDIM,
                                       bn_b + (size_t)i * HDIM,
                                       scale2, shift2, mblocks, 1.0f / N);

    if (i == 0) {
      k_bnfuse_b<<<gridNH4, blk, 0, stream>>>(z_b, scale2, shift2, vf, batch,
                                              hb2, N);
    } else if (i == 1) {
      k_bnapply_b1<<<gridNH4, blk, 0, stream>>>(z_b, scale2, shift2, fb2, N);
    } else {
      k_bnapply<<<gridNH4, blk, 0, stream>>>(y2, scale2, shift2, out_feats,
                                             (long long)(NH / 4), HDIM / 4, 0);
    }

    if (i == 1) {
      hipMemsetAsync(pooled, 0, (size_t)GNUM * HDIM * sizeof(float), stream);
      k_pool2_b<<<(N + 127) / 128, blk, 0, stream>>>(fb2, batch, pooled, N);
      k_add<<<(GNUM * HDIM + 255) / 256, blk, 0, stream>>>(pooled, vf, vin,
                                                           GNUM * HDIM);

      hipMemsetAsync(sum1, 0, (size_t)(2 * H2DIM + 2 * HDIM) * sizeof(float), stream);
      k_gemm<<<dim3(GNUM / 64, H2DIM / 64), blk, 0, stream>>>(
          vin, vw1, vb1, nullptr, nullptr, v1, GNUM, HDIM, H2DIM);
      k_colstats<<<(GNUM + 127) / 128, H2DIM, 0, stream>>>(v1, GNUM, H2DIM, 128,
                                                           sum1, ss1);
      k_bnfin<<<1, H2DIM, 0, stream>>>(sum1, ss1, vbn1g, vbn1b, scale1, shift1,
                                       H2DIM, 1.0f / GNUM);

      k_gemm<<<dim3(GNUM / 64, HDIM / 64), blk, 0, stream>>>(
          v1, vw2, vb2, scale1, shift1, vin, GNUM, H2DIM, HDIM);
      k_colstats<<<(GNUM + 127) / 128, HDIM, 0, stream>>>(vin, GNUM, HDIM, 128,
                                                          sum2, ss2);
      k_bnfin<<<1, HDIM, 0, stream>>>(sum2, ss2, vbn2g, vbn2b, scale2, shift2,
                                      HDIM, 1.0f / GNUM);
      k_bnapply<<<(GNUM * HDIM / 4 + 255) / 256, blk, 0, stream>>>(
          vin, scale2, shift2, vf, (long long)(GNUM * HDIM / 4), HDIM / 4, 1);
    }
  }

  hipMemsetAsync(pooled, 0, (size_t)GNUM * HDIM * sizeof(float), stream);
  hipMemsetAsync(counts, 0, (size_t)GNUM * sizeof(float), stream);
  k_pool2<<<(N + 127) / 128, blk, 0, stream>>>(out_feats, batch, pooled, counts, N);
  k_readout<<<(GNUM * HDIM + 255) / 256, blk, 0, stream>>>(pooled, counts, out_read,
                                                           GNUM * HDIM);
  hipMemcpyAsync(out_vf, vf, (size_t)GNUM * HDIM * sizeof(float),
                 hipMemcpyDeviceToDevice, stream);
}

// Round 14
// 785.316 us; speedup vs baseline: 1.0023x; 1.0023x over previous
//
#include <hip/hip_runtime.h>

// GIN encoder w/ virtual node, 3 layers, H=128. Round 14 (base: round 13):
// k_gemm_mfma: rolling register prefetch across the staging barrier — issue
// tile k+1's global loads after tile k's LDS-write barrier, hiding load
// latency under MFMA compute. Everything else frozen.

#define HDIM 128
#define H2DIM 256
#define GNUM 512
#define BN_EPS 1e-5f

typedef short bf16x8 __attribute__((ext_vector_type(8)));
typedef float f32x4 __attribute__((ext_vector_type(4)));
typedef unsigned int u32x4 __attribute__((ext_vector_type(4)));

__device__ __forceinline__ unsigned short f2bf(float f) {
  unsigned int u = __float_as_uint(f);
  u = (u + 0x7FFFu + ((u >> 16) & 1u)) >> 16;
  return (unsigned short)u;
}
__device__ __forceinline__ float bf2f(unsigned short s) {
  return __uint_as_float(((unsigned int)s) << 16);
}

// ---------------- elementwise / init ----------------

__global__ __launch_bounds__(256) void k_init_vf(const float* __restrict__ emb,
                                                 float* __restrict__ vf) {
  int idx = blockIdx.x * 256 + threadIdx.x;
  if (idx < GNUM * HDIM) vf[idx] = emb[idx & (HDIM - 1)];
}

// h(bf16) = feats(f32) (layer 0, no vf)
__global__ __launch_bounds__(256) void k_h_init(const float* __restrict__ feats,
                                                unsigned short* __restrict__ h,
                                                int N) {
  int idx = blockIdx.x * 256 + threadIdx.x;
  int total = N * (HDIM / 4);
  if (idx >= total) return;
  float4 v = ((const float4*)feats)[idx];
  ushort4 o;
  o.x = f2bf(v.x); o.y = f2bf(v.y); o.z = f2bf(v.z); o.w = f2bf(v.w);
  ((ushort4*)h)[idx] = o;
}

// h(bf16) = feats_b(bf16) + vf[batch]  (layer 2)
__global__ __launch_bounds__(256) void k_h_init_b(const unsigned short* __restrict__ fb,
                                                  const float* __restrict__ vf,
                                                  const int* __restrict__ batch,
                                                  unsigned short* __restrict__ h,
                                                  int N) {
  int idx = blockIdx.x * 256 + threadIdx.x;
  int total = N * (HDIM / 4);
  if (idx >= total) return;
  int n = idx >> 5;
  int c4 = idx & 31;
  ushort4 u = ((const ushort4*)fb)[idx];
  int g = batch[n];
  float4 w = ((const float4*)(vf + (size_t)g * HDIM))[c4];
  ushort4 o;
  o.x = f2bf(bf2f(u.x) + w.x);
  o.y = f2bf(bf2f(u.y) + w.y);
  o.z = f2bf(bf2f(u.z) + w.z);
  o.w = f2bf(bf2f(u.w) + w.w);
  ((ushort4*)h)[idx] = o;
}

// layer-0 epilogue: h(bf16) = relu(bn(y2 bf16)) + vf[batch]
__global__ __launch_bounds__(256) void k_bnfuse_b(const unsigned short* __restrict__ Y,
                                                  const float* __restrict__ scale,
                                                  const float* __restrict__ shift,
                                                  const float* __restrict__ vf,
                                                  const int* __restrict__ batch,
                                                  unsigned short* __restrict__ hout,
                                                  int N) {
  int idx = blockIdx.x * 256 + threadIdx.x;
  int total = N * (HDIM / 4);
  if (idx >= total) return;
  int n = idx >> 5;
  int c4 = idx & 31;
  int c = c4 * 4;
  ushort4 u = ((const ushort4*)Y)[idx];
  int g = batch[n];
  float4 w = ((const float4*)(vf + (size_t)g * HDIM))[c4];
  float vx = fmaxf(fmaf(bf2f(u.x), scale[c + 0], shift[c + 0]), 0.f) + w.x;
  float vy = fmaxf(fmaf(bf2f(u.y), scale[c + 1], shift[c + 1]), 0.f) + w.y;
  float vz = fmaxf(fmaf(bf2f(u.z), scale[c + 2], shift[c + 2]), 0.f) + w.z;
  float vw = fmaxf(fmaf(bf2f(u.w), scale[c + 3], shift[c + 3]), 0.f) + w.w;
  ushort4 o;
  o.x = f2bf(vx); o.y = f2bf(vy); o.z = f2bf(vz); o.w = f2bf(vw);
  ((ushort4*)hout)[idx] = o;
}

// layer-1 epilogue: fb2(bf16) = relu(bn(y2 bf16))
__global__ __launch_bounds__(256) void k_bnapply_b1(
    const unsigned short* __restrict__ Y, const float* __restrict__ scale,
    const float* __restrict__ shift, unsigned short* __restrict__ outb, int N) {
  int idx = blockIdx.x * 256 + threadIdx.x;
  int total = N * (HDIM / 4);
  if (idx >= total) return;
  int c = (idx & 31) * 4;
  ushort4 u = ((const ushort4*)Y)[idx];
  ushort4 o;
  o.x = f2bf(fmaxf(fmaf(bf2f(u.x), scale[c + 0], shift[c + 0]), 0.f));
  o.y = f2bf(fmaxf(fmaf(bf2f(u.y), scale[c + 1], shift[c + 1]), 0.f));
  o.z = f2bf(fmaxf(fmaf(bf2f(u.z), scale[c + 2], shift[c + 2]), 0.f));
  o.w = f2bf(fmaxf(fmaf(bf2f(u.w), scale[c + 3], shift[c + 3]), 0.f));
  ((ushort4*)outb)[idx] = o;
}

// layer-2 epilogue: out(f32) = bn(y2 f32), no relu
__global__ __launch_bounds__(256) void k_bnapply(const float* __restrict__ Y,
                                                 const float* __restrict__ scale,
                                                 const float* __restrict__ shift,
                                                 float* __restrict__ out,
                                                 long long total4, int Cq, int relu) {
  long long idx = (long long)blockIdx.x * 256 + threadIdx.x;
  if (idx >= total4) return;
  int c = (int)(idx % Cq) * 4;
  float4 v = ((const float4*)Y)[idx];
  v.x = fmaf(v.x, scale[c + 0], shift[c + 0]);
  v.y = fmaf(v.y, scale[c + 1], shift[c + 1]);
  v.z = fmaf(v.z, scale[c + 2], shift[c + 2]);
  v.w = fmaf(v.w, scale[c + 3], shift[c + 3]);
  if (relu) {
    v.x = fmaxf(v.x, 0.f); v.y = fmaxf(v.y, 0.f);
    v.z = fmaxf(v.z, 0.f); v.w = fmaxf(v.w, 0.f);
  }
  ((float4*)out)[idx] = v;
}

__global__ __launch_bounds__(256) void k_convw_all(const float* __restrict__ w1,
                                                   const float* __restrict__ w2,
                                                   unsigned short* __restrict__ wt1,
                                                   unsigned short* __restrict__ wt2) {
  int idx = blockIdx.x * 256 + threadIdx.x;
  const int P = 3 * HDIM * H2DIM;
  if (idx < P) {
    int i = idx / (H2DIM * HDIM);
    int o = idx % (H2DIM * HDIM);
    int n = o / HDIM;
    int k = o % HDIM;
    wt1[idx] = f2bf(w1[(size_t)i * HDIM * H2DIM + (size_t)k * H2DIM + n]);
  } else if (idx < 2 * P) {
    int o2 = idx - P;
    int i = o2 / (HDIM * H2DIM);
    int o = o2 % (HDIM * H2DIM);
    int n = o / H2DIM;
    int k = o % H2DIM;
    wt2[o2] = f2bf(w2[(size_t)i * H2DIM * HDIM + (size_t)k * HDIM + n]);
  }
}

// ---------------- CSR build ----------------

__global__ __launch_bounds__(256) void k_hist(const int* __restrict__ ei,
                                              int* __restrict__ deg, int E) {
  int e = blockIdx.x * 256 + threadIdx.x;
  if (e < E) atomicAdd(&deg[ei[E + e]], 1);
}

__global__ __launch_bounds__(256) void k_scan1(const int* __restrict__ deg,
                                               int* __restrict__ bsum, int N) {
  __shared__ int sh[256];
  int t = threadIdx.x;
  int base = blockIdx.x * 2048 + t * 8;
  int s = 0;
#pragma unroll
  for (int j = 0; j < 8; ++j) {
    int i = base + j;
    if (i < N) s += deg[i];
  }
  sh[t] = s;
  __syncthreads();
  for (int off = 128; off > 0; off >>= 1) {
    if (t < off) sh[t] += sh[t + off];
    __syncthreads();
  }
  if (t == 0) bsum[blockIdx.x] = sh[0];
}

__global__ __launch_bounds__(256) void k_scan2(int* __restrict__ bsum, int nb,
                                               int* __restrict__ row_ptr, int N) {
  __shared__ int sh[256];
  int t = threadIdx.x;
  int v = (t < nb) ? bsum[t] : 0;
  sh[t] = v;
  __syncthreads();
  for (int off = 1; off < 256; off <<= 1) {
    int add = (t >= off) ? sh[t - off] : 0;
    __syncthreads();
    sh[t] += add;
    __syncthreads();
  }
  if (t < nb) bsum[t] = sh[t] - v;
  if (t == 255) row_ptr[N] = sh[255];
}

__global__ __launch_bounds__(256) void k_scan3(const int* __restrict__ deg,
                                               const int* __restrict__ boff,
                                               int* __restrict__ row_ptr, int N) {
  __shared__ int sh[256];
  int t = threadIdx.x;
  int base = blockIdx.x * 2048 + t * 8;
  int d[8];
  int s = 0;
#pragma unroll
  for (int j = 0; j < 8; ++j) {
    int i = base + j;
    d[j] = (i < N) ? deg[i] : 0;
    s += d[j];
  }
  sh[t] = s;
  __syncthreads();
  for (int off = 1; off < 256; off <<= 1) {
    int add = (t >= off) ? sh[t - off] : 0;
    __syncthreads();
    sh[t] += add;
    __syncthreads();
  }
  int run = boff[blockIdx.x] + sh[t] - s;
#pragma unroll
  for (int j = 0; j < 8; ++j) {
    int i = base + j;
    if (i < N) {
      row_ptr[i] = run;
      run += d[j];
    }
  }
}

__global__ __launch_bounds__(256) void k_binA(const int* __restrict__ ei,
                                              const int* __restrict__ row_ptr,
                                              int* __restrict__ bktcur,
                                              int* __restrict__ staged,
                                              int E, int NB) {
  __shared__ int hist[512];
  __shared__ int lbase[512];
  int tid = threadIdx.x;
  hist[tid] = 0; hist[tid + 256] = 0;
  __syncthreads();
  int e0 = blockIdx.x * 4096;
#pragma unroll
  for (int j = 0; j < 16; ++j) {
    int e = e0 + j * 256 + tid;
    if (e < E) atomicAdd(&hist[ei[E + e] >> 8], 1);
  }
  __syncthreads();
  for (int t = tid; t < NB; t += 256) {
    int cgot = hist[t];
    if (cgot > 0) lbase[t] = row_ptr[t << 8] + atomicAdd(&bktcur[t], cgot);
    hist[t] = 0;
  }
  __syncthreads();
#pragma unroll
  for (int j = 0; j < 16; ++j) {
    int e = e0 + j * 256 + tid;
    if (e < E) {
      int d = ei[E + e];
      int b = d >> 8;
      int loc = atomicAdd(&hist[b], 1);
      staged[lbase[b] + loc] = (ei[e] << 8) | (d & 255);
    }
  }
}

__global__ __launch_bounds__(256) void k_binB(const int* __restrict__ row_ptr,
                                              const int* __restrict__ staged,
                                              int* __restrict__ csr, int N) {
  __shared__ int lcur[256];
  int b = blockIdx.x;
  int node0 = b << 8;
  int tid = threadIdx.x;
  int nend = min(node0 + 256, N);
  lcur[tid] = (node0 + tid < N) ? row_ptr[node0 + tid] : 0;
  __syncthreads();
  int s0 = row_ptr[node0];
  int s1 = row_ptr[nend];
  for (int j = s0 + tid; j < s1; j += 256) {
    int rec = staged[j];
    int pos = atomicAdd(&lcur[rec & 255], 1);
    csr[pos] = rec >> 8;
  }
}

// ---------------- aggregation (bf16) ----------------
__device__ __forceinline__ void acc8(float* a, uint4 v) {
  a[0] += bf2f((unsigned short)v.x); a[1] += bf2f((unsigned short)(v.x >> 16));
  a[2] += bf2f((unsigned short)v.y); a[3] += bf2f((unsigned short)(v.y >> 16));
  a[4] += bf2f((unsigned short)v.z); a[5] += bf2f((unsigned short)(v.z >> 16));
  a[6] += bf2f((unsigned short)v.w); a[7] += bf2f((unsigned short)(v.w >> 16));
}

__global__ __launch_bounds__(256) void k_aggregate(const unsigned short* __restrict__ h,
                                                   const int* __restrict__ row_ptr,
                                                   const int* __restrict__ csr,
                                                   unsigned short* __restrict__ z,
                                                   int N) {
  int n = blockIdx.x * 16 + (threadIdx.x >> 4);
  if (n >= N) return;
  int lane = threadIdx.x & 15;
  const uint4* __restrict__ hp = (const uint4*)h;
  float a[8];
  {
    uint4 u = hp[(size_t)n * 16 + lane];
    a[0] = bf2f((unsigned short)u.x); a[1] = bf2f((unsigned short)(u.x >> 16));
    a[2] = bf2f((unsigned short)u.y); a[3] = bf2f((unsigned short)(u.y >> 16));
    a[4] = bf2f((unsigned short)u.z); a[5] = bf2f((unsigned short)(u.z >> 16));
    a[6] = bf2f((unsigned short)u.w); a[7] = bf2f((unsigned short)(u.w >> 16));
  }
  int beg = row_ptr[n], end = row_ptr[n + 1];
  int j = beg;
  for (; j + 4 <= end; j += 4) {
    int s0 = csr[j], s1 = csr[j + 1], s2 = csr[j + 2], s3 = csr[j + 3];
    uint4 v0 = hp[(size_t)s0 * 16 + lane];
    uint4 v1 = hp[(size_t)s1 * 16 + lane];
    uint4 v2 = hp[(size_t)s2 * 16 + lane];
    uint4 v3 = hp[(size_t)s3 * 16 + lane];
    acc8(a, v0); acc8(a, v1); acc8(a, v2); acc8(a, v3);
  }
  for (; j < end; ++j) {
    uint4 v = hp[(size_t)csr[j] * 16 + lane];
    acc8(a, v);
  }
  u32x4 o;
  o.x = (unsigned int)f2bf(a[0]) | ((unsigned int)f2bf(a[1]) << 16);
  o.y = (unsigned int)f2bf(a[2]) | ((unsigned int)f2bf(a[3]) << 16);
  o.z = (unsigned int)f2bf(a[4]) | ((unsigned int)f2bf(a[5]) << 16);
  o.w = (unsigned int)f2bf(a[6]) | ((unsigned int)f2bf(a[7]) << 16);
  __builtin_nontemporal_store(o, (u32x4*)z + (size_t)n * 16 + lane);
}

// ---------------- MFMA GEMM: 64x128 tile, BK=64, register-prefetch pipeline --
#define LDA_S 76
__global__ __launch_bounds__(256) void k_gemm_mfma(
    const unsigned short* __restrict__ A, const unsigned short* __restrict__ Wt,
    const float* __restrict__ bias, const float* __restrict__ kscale,
    const float* __restrict__ kshift, void* __restrict__ Cout, int outBf16,
    float* __restrict__ pS, float* __restrict__ pQ, int mblocks,
    int M, int K, int Nc) {
  __shared__ unsigned short As[64 * LDA_S];
  __shared__ unsigned short Bs[128 * LDA_S];
  __shared__ float redS[128];
  __shared__ float redQ[128];
  __shared__ float ksc[256];
  __shared__ float ksh[256];

  int tid = threadIdx.x;
  int lane = tid & 63;
  int wid = tid >> 6;
  int wrow = (wid & 1) * 32;
  int wcol = (wid >> 1) * 64;
  int bm = blockIdx.x * 64;
  int bn = blockIdx.y * 128;
  int lrow = lane & 15;
  int lkg = lane >> 4;

  if (tid < 128) { redS[tid] = 0.f; redQ[tid] = 0.f; }
  if (kscale) {
    for (int k = tid; k < K; k += 256) { ksc[k] = kscale[k]; ksh[k] = kshift[k]; }
  }

  f32x4 acc[2][4];
#pragma unroll
  for (int r = 0; r < 2; ++r)
#pragma unroll
    for (int c = 0; c < 4; ++c) acc[r][c] = (f32x4){0.f, 0.f, 0.f, 0.f};

  // rolling register prefetch: tile kt held in pA/pB, next tile issued after
  // the staging barrier so its latency hides under this tile's compute.
  bf16x8 pA[2], pB[4];
  {
#pragma unroll
    for (int it = 0; it < 2; ++it) {
      int ga = it * 256 + tid;
      int row = ga >> 3, g = ga & 7;
      int grow = bm + row;
      pA[it] = (bf16x8){0, 0, 0, 0, 0, 0, 0, 0};
      if (grow < M) pA[it] = *(const bf16x8*)(A + (size_t)grow * K + g * 8);
    }
#pragma unroll
    for (int it = 0; it < 4; ++it) {
      int gb = it * 256 + tid;
      int row = gb >> 3, g = gb & 7;
      pB[it] = *(const bf16x8*)(Wt + (size_t)(bn + row) * K + g * 8);
    }
  }

  for (int kt = 0; kt < K; kt += 64) {
    __syncthreads();
    // write prefetched tile to LDS (kscale transform applied here)
#pragma unroll
    for (int it = 0; it < 2; ++it) {
      int ga = it * 256 + tid;
      int row = ga >> 3, g = ga & 7;
      bf16x8 av = pA[it];
      if (kscale) {
        int k0 = kt + g * 8;
#pragma unroll
        for (int j = 0; j < 8; ++j) {
          float f = bf2f((unsigned short)av[j]);
          f = fmaxf(fmaf(f, ksc[k0 + j], ksh[k0 + j]), 0.f);
          av[j] = (short)f2bf(f);
        }
      }
      *(bf16x8*)(As + row * LDA_S + g * 8) = av;
    }
#pragma unroll
    for (int it = 0; it < 4; ++it) {
      int gb = it * 256 + tid;
      int row = gb >> 3, g = gb & 7;
      *(bf16x8*)(Bs + row * LDA_S + g * 8) = pB[it];
    }
    __syncthreads();
    // issue next tile's loads (consumed at next iteration's LDS-write)
    if (kt + 64 < K) {
      int kn = kt + 64;
#pragma unroll
      for (int it = 0; it < 2; ++it) {
        int ga = it * 256 + tid;
        int row = ga >> 3, g = ga & 7;
        int grow = bm + row;
        pA[it] = (bf16x8){0, 0, 0, 0, 0, 0, 0, 0};
        if (grow < M) pA[it] = *(const bf16x8*)(A + (size_t)grow * K + kn + g * 8);
      }
#pragma unroll
      for (int it = 0; it < 4; ++it) {
        int gb = it * 256 + tid;
        int row = gb >> 3, g = gb & 7;
        pB[it] = *(const bf16x8*)(Wt + (size_t)(bn + row) * K + kn + g * 8);
      }
    }
    // compute current tile from LDS
#pragma unroll
    for (int ks = 0; ks < 2; ++ks) {
      int goff = ks * 4 + lkg;
      bf16x8 af[2], bfr[4];
#pragma unroll
      for (int rf = 0; rf < 2; ++rf)
        af[rf] = *(const bf16x8*)(As + (wrow + rf * 16 + lrow) * LDA_S + goff * 8);
#pragma unroll
      for (int cf = 0; cf < 4; ++cf)
        bfr[cf] = *(const bf16x8*)(Bs + (wcol + cf * 16 + lrow) * LDA_S + goff * 8);
#pragma unroll
      for (int rf = 0; rf < 2; ++rf)
#pragma unroll
        for (int cf = 0; cf < 4; ++cf)
          acc[rf][cf] = __builtin_amdgcn_mfma_f32_16x16x32_bf16(
              af[rf], bfr[cf], acc[rf][cf], 0, 0, 0);
    }
  }

#pragma unroll
  for (int cf = 0; cf < 4; ++cf) {
    int lcol = wcol + cf * 16 + lrow;
    float bb = bias[bn + lcol];
    float s = 0.f, q = 0.f;
#pragma unroll
    for (int rf = 0; rf < 2; ++rf) {
#pragma unroll
      for (int j = 0; j < 4; ++j) {
        float v = acc[rf][cf][j] + bb;
        acc[rf][cf][j] = v;
        int grow = bm + wrow + rf * 16 + lkg * 4 + j;
        if (grow < M) { s += v; q += v * v; }
      }
    }
    s += __shfl_xor(s, 16); s += __shfl_xor(s, 32);
    q += __shfl_xor(q, 16); q += __shfl_xor(q, 32);
    if (lane < 16) {
      atomicAdd(&redS[lcol], s);
      atomicAdd(&redQ[lcol], q);
    }
  }

#pragma unroll
  for (int cf = 0; cf < 4; ++cf) {
    int col = bn + wcol + cf * 16 + lrow;
#pragma unroll
    for (int rf = 0; rf < 2; ++rf) {
#pragma unroll
      for (int j = 0; j < 4; ++j) {
        int grow = bm + wrow + rf * 16 + lkg * 4 + j;
        if (grow < M) {
          float v = acc[rf][cf][j];
          if (outBf16)
            ((unsigned short*)Cout)[(size_t)grow * Nc + col] = f2bf(v);
          else
            ((float*)Cout)[(size_t)grow * Nc + col] = v;
        }
      }
    }
  }
  __syncthreads();
  if (tid < 128) {
    size_t off = (size_t)(bn + tid) * mblocks + blockIdx.x;
    pS[off] = redS[tid];
    pQ[off] = redQ[tid];
  }
}

__global__ __launch_bounds__(256) void k_bnfin2(const float* __restrict__ pS,
                                                const float* __restrict__ pQ,
                                                const float* __restrict__ g,
                                                const float* __restrict__ b,
                                                float* __restrict__ scale,
                                                float* __restrict__ shift,
                                                int mblocks, float invM) {
  __shared__ float shS[256], shQ[256];
  int c = blockIdx.x;
  int t = threadIdx.x;
  const float* rs = pS + (size_t)c * mblocks;
  const float* rq = pQ + (size_t)c * mblocks;
  float s = 0.f, q = 0.f;
  for (int j = t; j < mblocks; j += 256) { s += rs[j]; q += rq[j]; }
  shS[t] = s; shQ[t] = q;
  __syncthreads();
  for (int off = 128; off > 0; off >>= 1) {
    if (t < off) { shS[t] += shS[t + off]; shQ[t] += shQ[t + off]; }
    __syncthreads();
  }
  if (t == 0) {
    float mean = shS[0] * invM;
    float var = shQ[0] * invM - mean * mean;
    float inv = rsqrtf(var + BN_EPS);
    float sc = g[c] * inv;
    scale[c] = sc;
    shift[c] = fmaf(-mean, sc, b[c]);
  }
}

// ---------------- GEMM 64x64 f32 (vn-MLP, 512 rows) ----------------
__global__ __launch_bounds__(256) void k_gemm(const float* __restrict__ A,
                                              const float* __restrict__ B,
                                              const float* __restrict__ bias,
                                              const float* __restrict__ kscale,
                                              const float* __restrict__ kshift,
                                              float* __restrict__ C,
                                              int M, int K, int Nc) {
  __shared__ float As[16][65];
  __shared__ float Bs[16][65];
  int tid = threadIdx.x;
  int bm = blockIdx.x * 64;
  int bn = blockIdx.y * 64;
  int trow = (tid >> 4) << 2;
  int tcol = (tid & 15) << 2;
  float acc[4][4] = {};

  int arow = tid >> 2;
  int ak = (tid & 3) << 2;
  int bt4 = tid << 2;
  int bk = bt4 >> 6;
  int bcol = bt4 & 63;

  for (int kt = 0; kt < K; kt += 16) {
    float4 av = make_float4(0.f, 0.f, 0.f, 0.f);
    int grow = bm + arow;
    if (grow < M) av = *(const float4*)(A + (size_t)grow * K + kt + ak);
    if (kscale) {
      int k0 = kt + ak;
      av.x = fmaxf(fmaf(av.x, kscale[k0 + 0], kshift[k0 + 0]), 0.f);
      av.y = fmaxf(fmaf(av.y, kscale[k0 + 1], kshift[k0 + 1]), 0.f);
      av.z = fmaxf(fmaf(av.z, kscale[k0 + 2], kshift[k0 + 2]), 0.f);
      av.w = fmaxf(fmaf(av.w, kscale[k0 + 3], kshift[k0 + 3]), 0.f);
    }
    float4 bv = *(const float4*)(B + (size_t)(kt + bk) * Nc + bn + bcol);
    __syncthreads();
    As[ak + 0][arow] = av.x;
    As[ak + 1][arow] = av.y;
    As[ak + 2][arow] = av.z;
    As[ak + 3][arow] = av.w;
    Bs[bk][bcol + 0] = bv.x;
    Bs[bk][bcol + 1] = bv.y;
    Bs[bk][bcol + 2] = bv.z;
    Bs[bk][bcol + 3] = bv.w;
    __syncthreads();
#pragma unroll
    for (int k = 0; k < 16; ++k) {
      float a0 = As[k][trow + 0], a1 = As[k][trow + 1];
      float a2 = As[k][trow + 2], a3 = As[k][trow + 3];
      float b0 = Bs[k][tcol + 0], b1 = Bs[k][tcol + 1];
      float b2 = Bs[k][tcol + 2], b3 = Bs[k][tcol + 3];
      acc[0][0] = fmaf(a0, b0, acc[0][0]); acc[0][1] = fmaf(a0, b1, acc[0][1]);
      acc[0][2] = fmaf(a0, b2, acc[0][2]); acc[0][3] = fmaf(a0, b3, acc[0][3]);
      acc[1][0] = fmaf(a1, b0, acc[1][0]); acc[1][1] = fmaf(a1, b1, acc[1][1]);
      acc[1][2] = fmaf(a1, b2, acc[1][2]); acc[1][3] = fmaf(a1, b3, acc[1][3]);
      acc[2][0] = fmaf(a2, b0, acc[2][0]); acc[2][1] = fmaf(a2, b1, acc[2][1]);
      acc[2][2] = fmaf(a2, b2, acc[2][2]); acc[2][3] = fmaf(a2, b3, acc[2][3]);
      acc[3][0] = fmaf(a3, b0, acc[3][0]); acc[3][1] = fmaf(a3, b1, acc[3][1]);
      acc[3][2] = fmaf(a3, b2, acc[3][2]); acc[3][3] = fmaf(a3, b3, acc[3][3]);
    }
  }
#pragma unroll
  for (int r = 0; r < 4; ++r) {
    int grow = bm + trow + r;
    if (grow < M) {
      float4 o;
      o.x = acc[r][0] + bias[bn + tcol + 0];
      o.y = acc[r][1] + bias[bn + tcol + 1];
      o.z = acc[r][2] + bias[bn + tcol + 2];
      o.w = acc[r][3] + bias[bn + tcol + 3];
      *(float4*)(C + (size_t)grow * Nc + bn + tcol) = o;
    }
  }
}

// ---------------- BN stats / finalize (vn-MLP path) ----------------

__global__ void k_colstats(const float* __restrict__ Y, int M, int C, int stripe,
                           float* __restrict__ sum, float* __restrict__ sumsq) {
  int c = threadIdx.x;
  int r0 = blockIdx.x * stripe;
  int r1 = min(r0 + stripe, M);
  float s = 0.f, ss = 0.f;
  for (int r = r0; r < r1; ++r) {
    float v = Y[(size_t)r * C + c];
    s += v; ss += v * v;
  }
  atomicAdd(&sum[c], s);
  atomicAdd(&sumsq[c], ss);
}

__global__ void k_bnfin(const float* __restrict__ sum, const float* __restrict__ sumsq,
                        const float* __restrict__ g, const float* __restrict__ b,
                        float* __restrict__ scale, float* __restrict__ shift,
                        int C, float invM) {
  int c = threadIdx.x;
  if (c >= C) return;
  float mean = sum[c] * invM;
  float var = sumsq[c] * invM - mean * mean;
  float inv = rsqrtf(var + BN_EPS);
  float sc = g[c] * inv;
  scale[c] = sc;
  shift[c] = fmaf(-mean, sc, b[c]);
}

// ---------------- pooling / readout / small ops ----------------

__global__ __launch_bounds__(256) void k_pool2(const float* __restrict__ X,
                                               const int* __restrict__ batch,
                                               float* __restrict__ pooled,
                                               float* __restrict__ counts, int N) {
  int c = threadIdx.x & 127;
  int half = threadIdx.x >> 7;
  int base = blockIdx.x * 128 + half * 64;
  if (base >= N) return;
  int lim = min(64, N - base);
  int g = batch[base];
  float acc = 0.f, cnt = 0.f;
  for (int r = 0; r < lim; ++r) {
    int bg = batch[base + r];
    if (bg != g) {
      atomicAdd(&pooled[(size_t)g * HDIM + c], acc);
      if (c == 0 && counts) atomicAdd(&counts[g], cnt);
      acc = 0.f; cnt = 0.f; g = bg;
    }
    acc += X[(size_t)(base + r) * HDIM + c];
    cnt += 1.f;
  }
  atomicAdd(&pooled[(size_t)g * HDIM + c], acc);
  if (c == 0 && counts) atomicAdd(&counts[g], cnt);
}

__global__ __launch_bounds__(256) void k_pool2_b(const unsigned short* __restrict__ X,
                                                 const int* __restrict__ batch,
                                                 float* __restrict__ pooled, int N) {
  int c = threadIdx.x & 127;
  int half = threadIdx.x >> 7;
  int base = blockIdx.x * 128 + half * 64;
  if (base >= N) return;
  int lim = min(64, N - base);
  int g = batch[base];
  float acc = 0.f;
  for (int r = 0; r < lim; ++r) {
    int bg = batch[base + r];
    if (bg != g) {
      atomicAdd(&pooled[(size_t)g * HDIM + c], acc);
      acc = 0.f; g = bg;
    }
    acc += bf2f(X[(size_t)(base + r) * HDIM + c]);
  }
  atomicAdd(&pooled[(size_t)g * HDIM + c], acc);
}

__global__ __launch_bounds__(256) void k_add(const float* __restrict__ a,
                                             const float* __restrict__ b,
                                             float* __restrict__ o, int n) {
  int idx = blockIdx.x * 256 + threadIdx.x;
  if (idx < n) o[idx] = a[idx] + b[idx];
}

__global__ __launch_bounds__(256) void k_readout(const float* __restrict__ pooled,
                                                 const float* __restrict__ counts,
                                                 float* __restrict__ out, int n) {
  int idx = blockIdx.x * 256 + threadIdx.x;
  if (idx >= n) return;
  int g = idx >> 7;
  out[idx] = pooled[idx] / fmaxf(counts[g], 1.0f);
}

// ---------------- launch ----------------

extern "C" void kernel_launch(void* const* d_in, const int* in_sizes, int n_in,
                              void* d_out, int out_size, void* d_ws, size_t ws_size,
                              hipStream_t stream) {
  const float* x       = (const float*)d_in[0];
  const int*   ei      = (const int*)d_in[1];
  const int*   batch   = (const int*)d_in[2];
  const float* conv_w1 = (const float*)d_in[4];
  const float* conv_b1 = (const float*)d_in[5];
  const float* conv_bng = (const float*)d_in[6];
  const float* conv_bnb = (const float*)d_in[7];
  const float* conv_w2 = (const float*)d_in[8];
  const float* conv_b2 = (const float*)d_in[9];
  const float* bn_g    = (const float*)d_in[10];
  const float* bn_b    = (const float*)d_in[11];
  const float* vn_emb  = (const float*)d_in[12];
  const float* vw1     = (const float*)d_in[13];
  const float* vb1     = (const float*)d_in[14];
  const float* vbn1g   = (const float*)d_in[15];
  const float* vbn1b   = (const float*)d_in[16];
  const float* vw2     = (const float*)d_in[17];
  const float* vb2     = (const float*)d_in[18];
  const float* vbn2g   = (const float*)d_in[19];
  const float* vbn2b   = (const float*)d_in[20];

  const int N = in_sizes[2];
  const int E = in_sizes[1] / 2;
  const int L = 3;

  const size_t NH  = (size_t)N * HDIM;
  const size_t NH2 = (size_t)N * H2DIM;

  float*          y2   = (float*)d_ws;
  unsigned short* h_b  = (unsigned short*)d_ws;
  unsigned short* z_b  = h_b + NH;            // also y2b (bf16 y2, layers 0/1)
  unsigned short* y1_b = z_b + NH;
  unsigned short* wt1b = y1_b + NH2;
  unsigned short* wt2b = wt1b + (size_t)3 * H2DIM * HDIM;
  float* sum1   = (float*)(wt2b + (size_t)3 * HDIM * H2DIM);
  float* ss1    = sum1 + H2DIM;
  float* sum2   = ss1 + H2DIM;
  float* ss2    = sum2 + HDIM;
  float* scale1 = ss2 + HDIM;
  float* shift1 = scale1 + H2DIM;
  float* scale2 = shift1 + H2DIM;
  float* shift2 = scale2 + HDIM;
  float* vf     = shift2 + HDIM;
  float* pooled = vf + (size_t)GNUM * HDIM;
  float* vin    = pooled + (size_t)GNUM * HDIM;
  float* v1     = vin + (size_t)GNUM * HDIM;
  float* counts = v1 + (size_t)GNUM * H2DIM;
  int*   cursor = (int*)(counts + GNUM);
  int*   bktcur = cursor + N;
  int*   row_ptr = bktcur + 512;
  int*   csr    = row_ptr + N + 1;
  int*   staged = csr + E;
  int*   bsum   = staged + E;
  unsigned short* hb2 = (unsigned short*)(bsum + 256);
  unsigned short* fb2 = hb2 + NH;             // bf16 feats copy (layer-1 out)

  const int mblocks = (N + 63) / 64;
  float* pS = (float*)staged;   // reuse: dead after CSR build
  float* pQ = pS + (size_t)256 * mblocks;

  float* out_feats = (float*)d_out;
  float* out_read  = out_feats + NH;
  float* out_vf    = out_read + (size_t)GNUM * HDIM;

  dim3 blk(256);
  const int gridNH4 = (int)((NH / 4 + 255) / 256);
  const int gridE = (E + 255) / 256;
  const int nb = (N + 2047) / 2048;
  const int NB = (N + 255) >> 8;

  // ---- CSR build ----
  hipMemsetAsync(cursor, 0, (size_t)(N + 512) * sizeof(int), stream);
  k_hist<<<gridE, blk, 0, stream>>>(ei, cursor, E);
  k_scan1<<<nb, blk, 0, stream>>>(cursor, bsum, N);
  k_scan2<<<1, blk, 0, stream>>>(bsum, nb, row_ptr, N);
  k_scan3<<<nb, blk, 0, stream>>>(cursor, bsum, row_ptr, N);
  k_binA<<<(E + 4095) / 4096, blk, 0, stream>>>(ei, row_ptr, bktcur, staged, E, NB);
  k_binB<<<NB, blk, 0, stream>>>(row_ptr, staged, csr, N);

  // ---- weight conversion ----
  k_convw_all<<<(2 * 3 * HDIM * H2DIM + 255) / 256, blk, 0, stream>>>(
      conv_w1, conv_w2, wt1b, wt2b);

  k_init_vf<<<(GNUM * HDIM + 255) / 256, blk, 0, stream>>>(vn_emb, vf);

  for (int i = 0; i < L; ++i) {
    if (i == 0)
      k_h_init<<<gridNH4, blk, 0, stream>>>(x, h_b, N);
    else if (i == 2)
      k_h_init_b<<<gridNH4, blk, 0, stream>>>(fb2, vf, batch, h_b, N);
    const unsigned short* hcur = (i == 1) ? hb2 : h_b;

    k_aggregate<<<(N + 15) / 16, blk, 0, stream>>>(hcur, row_ptr, csr, z_b, N);

    // GEMM1: y1_b(bf16) = z_b @ W1[i] + b1[i], partial-buffer stats
    k_gemm_mfma<<<dim3(mblocks, H2DIM / 128), blk, 0, stream>>>(
        z_b, wt1b + (size_t)i * H2DIM * HDIM, conv_b1 + (size_t)i * H2DIM,
        nullptr, nullptr, y1_b, 1, pS, pQ, mblocks, N, HDIM, H2DIM);
    k_bnfin2<<<H2DIM, blk, 0, stream>>>(pS, pQ, conv_bng + (size_t)i * H2DIM,
                                        conv_bnb + (size_t)i * H2DIM,
                                        scale1, shift1, mblocks, 1.0f / N);

    // GEMM2: y2 = relu(bn(y1)) @ W2[i] + b2[i]; bf16 output into z_b for i<2
    int outBf = (i < 2) ? 1 : 0;
    void* y2dst = (i < 2) ? (void*)z_b : (void*)y2;
    k_gemm_mfma<<<dim3(mblocks, HDIM / 128), blk, 0, stream>>>(
        y1_b, wt2b + (size_t)i * HDIM * H2DIM, conv_b2 + (size_t)i * HDIM,
        scale1, shift1, y2dst, outBf, pS, pQ, mblocks, N, H2DIM, HDIM);
    k_bnfin2<<<HDIM, blk, 0, stream>>>(pS, pQ, bn_g + (size_t)i * HDIM,
                                       bn_b + (size_t)i * HDIM,
                                       scale2, shift2, mblocks, 1.0f / N);

    if (i == 0) {
      k_bnfuse_b<<<gridNH4, blk, 0, stream>>>(z_b, scale2, shift2, vf, batch,
                                              hb2, N);
    } else if (i == 1) {
      k_bnapply_b1<<<gridNH4, blk, 0, stream>>>(z_b, scale2, shift2, fb2, N);
    } else {
      k_bnapply<<<gridNH4, blk, 0, stream>>>(y2, scale2, shift2, out_feats,
                                             (long long)(NH / 4), HDIM / 4, 0);
    }

    if (i == 1) {
      hipMemsetAsync(pooled, 0, (size_t)GNUM * HDIM * sizeof(float), stream);
      k_pool2_b<<<(N + 127) / 128, blk, 0, stream>>>(fb2, batch, pooled, N);
      k_add<<<(GNUM * HDIM + 255) / 256, blk, 0, stream>>>(pooled, vf, vin,
                                                           GNUM * HDIM);

      hipMemsetAsync(sum1, 0, (size_t)(2 * H2DIM + 2 * HDIM) * sizeof(float), stream);
      k_gemm<<<dim3(GNUM / 64, H2DIM / 64), blk, 0, stream>>>(
          vin, vw1, vb1, nullptr, nullptr, v1, GNUM, HDIM, H2DIM);
      k_colstats<<<(GNUM + 127) / 128, H2DIM, 0, stream>>>(v1, GNUM, H2DIM, 128,
                                                           sum1, ss1);
      k_bnfin<<<1, H2DIM, 0, stream>>>(sum1, ss1, vbn1g, vbn1b, scale1, shift1,
                                       H2DIM, 1.0f / GNUM);

      k_gemm<<<dim3(GNUM / 64, HDIM / 64), blk, 0, stream>>>(
          v1, vw2, vb2, scale1, shift1, vin, GNUM, H2DIM, HDIM);
      k_colstats<<<(GNUM + 127) / 128, HDIM, 0, stream>>>(vin, GNUM, HDIM, 128,
                                                          sum2, ss2);
      k_bnfin<<<1, HDIM, 0, stream>>>(sum2, ss2, vbn2g, vbn2b, scale2, shift2,
                                      HDIM, 1.0f / GNUM);
      k_bnapply<<<(GNUM * HDIM / 4 + 255) / 256, blk, 0, stream>>>(
          vin, scale2, shift2, vf, (long long)(GNUM * HDIM / 4), HDIM / 4, 1);
    }
  }

  hipMemsetAsync(pooled, 0, (size_t)GNUM * HDIM * sizeof(float), stream);
  hipMemsetAsync(counts, 0, (size_t)GNUM * sizeof(float), stream);
  k_pool2<<<(N + 127) / 128, blk, 0, stream>>>(out_feats, batch, pooled, counts, N);
  k_readout<<<(GNUM * HDIM + 255) / 256, blk, 0, stream>>>(pooled, counts, out_read,
                                                           GNUM * HDIM);
  hipMemcpyAsync(out_vf, vf, (size_t)GNUM * HDIM * sizeof(float),
                 hipMemcpyDeviceToDevice, stream);
}

// Round 15
// 781.352 us; speedup vs baseline: 1.0074x; 1.0051x over previous
//
#include <hip/hip_runtime.h>

// GIN encoder w/ virtual node, 3 layers, H=128. Round 15 (base: round 13):
// k_gemm_mfma staging via __builtin_amdgcn_global_load_lds (width 16) with
// XOR-swizzled linear LDS layout (slot = g ^ (row&7)); A keeps register path
// when kscale is active (BN transform), writing the same swizzled layout.

#define HDIM 128
#define H2DIM 256
#define GNUM 512
#define BN_EPS 1e-5f

typedef short bf16x8 __attribute__((ext_vector_type(8)));
typedef float f32x4 __attribute__((ext_vector_type(4)));
typedef unsigned int u32x4 __attribute__((ext_vector_type(4)));

__device__ __forceinline__ unsigned short f2bf(float f) {
  unsigned int u = __float_as_uint(f);
  u = (u + 0x7FFFu + ((u >> 16) & 1u)) >> 16;
  return (unsigned short)u;
}
__device__ __forceinline__ float bf2f(unsigned short s) {
  return __uint_as_float(((unsigned int)s) << 16);
}

__device__ __forceinline__ void gload_lds16(const void* gp, void* lp) {
  __builtin_amdgcn_global_load_lds(
      (const __attribute__((address_space(1))) void*)gp,
      (__attribute__((address_space(3))) void*)lp, 16, 0, 0);
}

// ---------------- elementwise / init ----------------

__global__ __launch_bounds__(256) void k_init_vf(const float* __restrict__ emb,
                                                 float* __restrict__ vf) {
  int idx = blockIdx.x * 256 + threadIdx.x;
  if (idx < GNUM * HDIM) vf[idx] = emb[idx & (HDIM - 1)];
}

__global__ __launch_bounds__(256) void k_h_init(const float* __restrict__ feats,
                                                unsigned short* __restrict__ h,
                                                int N) {
  int idx = blockIdx.x * 256 + threadIdx.x;
  int total = N * (HDIM / 4);
  if (idx >= total) return;
  float4 v = ((const float4*)feats)[idx];
  ushort4 o;
  o.x = f2bf(v.x); o.y = f2bf(v.y); o.z = f2bf(v.z); o.w = f2bf(v.w);
  ((ushort4*)h)[idx] = o;
}

__global__ __launch_bounds__(256) void k_h_init_b(const unsigned short* __restrict__ fb,
                                                  const float* __restrict__ vf,
                                                  const int* __restrict__ batch,
                                                  unsigned short* __restrict__ h,
                                                  int N) {
  int idx = blockIdx.x * 256 + threadIdx.x;
  int total = N * (HDIM / 4);
  if (idx >= total) return;
  int n = idx >> 5;
  int c4 = idx & 31;
  ushort4 u = ((const ushort4*)fb)[idx];
  int g = batch[n];
  float4 w = ((const float4*)(vf + (size_t)g * HDIM))[c4];
  ushort4 o;
  o.x = f2bf(bf2f(u.x) + w.x);
  o.y = f2bf(bf2f(u.y) + w.y);
  o.z = f2bf(bf2f(u.z) + w.z);
  o.w = f2bf(bf2f(u.w) + w.w);
  ((ushort4*)h)[idx] = o;
}

__global__ __launch_bounds__(256) void k_bnfuse_b(const unsigned short* __restrict__ Y,
                                                  const float* __restrict__ scale,
                                                  const float* __restrict__ shift,
                                                  const float* __restrict__ vf,
                                                  const int* __restrict__ batch,
                                                  unsigned short* __restrict__ hout,
                                                  int N) {
  int idx = blockIdx.x * 256 + threadIdx.x;
  int total = N * (HDIM / 4);
  if (idx >= total) return;
  int n = idx >> 5;
  int c4 = idx & 31;
  int c = c4 * 4;
  ushort4 u = ((const ushort4*)Y)[idx];
  int g = batch[n];
  float4 w = ((const float4*)(vf + (size_t)g * HDIM))[c4];
  float vx = fmaxf(fmaf(bf2f(u.x), scale[c + 0], shift[c + 0]), 0.f) + w.x;
  float vy = fmaxf(fmaf(bf2f(u.y), scale[c + 1], shift[c + 1]), 0.f) + w.y;
  float vz = fmaxf(fmaf(bf2f(u.z), scale[c + 2], shift[c + 2]), 0.f) + w.z;
  float vw = fmaxf(fmaf(bf2f(u.w), scale[c + 3], shift[c + 3]), 0.f) + w.w;
  ushort4 o;
  o.x = f2bf(vx); o.y = f2bf(vy); o.z = f2bf(vz); o.w = f2bf(vw);
  ((ushort4*)hout)[idx] = o;
}

__global__ __launch_bounds__(256) void k_bnapply_b1(
    const unsigned short* __restrict__ Y, const float* __restrict__ scale,
    const float* __restrict__ shift, unsigned short* __restrict__ outb, int N) {
  int idx = blockIdx.x * 256 + threadIdx.x;
  int total = N * (HDIM / 4);
  if (idx >= total) return;
  int c = (idx & 31) * 4;
  ushort4 u = ((const ushort4*)Y)[idx];
  ushort4 o;
  o.x = f2bf(fmaxf(fmaf(bf2f(u.x), scale[c + 0], shift[c + 0]), 0.f));
  o.y = f2bf(fmaxf(fmaf(bf2f(u.y), scale[c + 1], shift[c + 1]), 0.f));
  o.z = f2bf(fmaxf(fmaf(bf2f(u.z), scale[c + 2], shift[c + 2]), 0.f));
  o.w = f2bf(fmaxf(fmaf(bf2f(u.w), scale[c + 3], shift[c + 3]), 0.f));
  ((ushort4*)outb)[idx] = o;
}

__global__ __launch_bounds__(256) void k_bnapply(const float* __restrict__ Y,
                                                 const float* __restrict__ scale,
                                                 const float* __restrict__ shift,
                                                 float* __restrict__ out,
                                                 long long total4, int Cq, int relu) {
  long long idx = (long long)blockIdx.x * 256 + threadIdx.x;
  if (idx >= total4) return;
  int c = (int)(idx % Cq) * 4;
  float4 v = ((const float4*)Y)[idx];
  v.x = fmaf(v.x, scale[c + 0], shift[c + 0]);
  v.y = fmaf(v.y, scale[c + 1], shift[c + 1]);
  v.z = fmaf(v.z, scale[c + 2], shift[c + 2]);
  v.w = fmaf(v.w, scale[c + 3], shift[c + 3]);
  if (relu) {
    v.x = fmaxf(v.x, 0.f); v.y = fmaxf(v.y, 0.f);
    v.z = fmaxf(v.z, 0.f); v.w = fmaxf(v.w, 0.f);
  }
  ((float4*)out)[idx] = v;
}

__global__ __launch_bounds__(256) void k_convw_all(const float* __restrict__ w1,
                                                   const float* __restrict__ w2,
                                                   unsigned short* __restrict__ wt1,
                                                   unsigned short* __restrict__ wt2) {
  int idx = blockIdx.x * 256 + threadIdx.x;
  const int P = 3 * HDIM * H2DIM;
  if (idx < P) {
    int i = idx / (H2DIM * HDIM);
    int o = idx % (H2DIM * HDIM);
    int n = o / HDIM;
    int k = o % HDIM;
    wt1[idx] = f2bf(w1[(size_t)i * HDIM * H2DIM + (size_t)k * H2DIM + n]);
  } else if (idx < 2 * P) {
    int o2 = idx - P;
    int i = o2 / (HDIM * H2DIM);
    int o = o2 % (HDIM * H2DIM);
    int n = o / H2DIM;
    int k = o % H2DIM;
    wt2[o2] = f2bf(w2[(size_t)i * H2DIM * HDIM + (size_t)k * HDIM + n]);
  }
}

// ---------------- CSR build ----------------

__global__ __launch_bounds__(256) void k_hist(const int* __restrict__ ei,
                                              int* __restrict__ deg, int E) {
  int e = blockIdx.x * 256 + threadIdx.x;
  if (e < E) atomicAdd(&deg[ei[E + e]], 1);
}

__global__ __launch_bounds__(256) void k_scan1(const int* __restrict__ deg,
                                               int* __restrict__ bsum, int N) {
  __shared__ int sh[256];
  int t = threadIdx.x;
  int base = blockIdx.x * 2048 + t * 8;
  int s = 0;
#pragma unroll
  for (int j = 0; j < 8; ++j) {
    int i = base + j;
    if (i < N) s += deg[i];
  }
  sh[t] = s;
  __syncthreads();
  for (int off = 128; off > 0; off >>= 1) {
    if (t < off) sh[t] += sh[t + off];
    __syncthreads();
  }
  if (t == 0) bsum[blockIdx.x] = sh[0];
}

__global__ __launch_bounds__(256) void k_scan2(int* __restrict__ bsum, int nb,
                                               int* __restrict__ row_ptr, int N) {
  __shared__ int sh[256];
  int t = threadIdx.x;
  int v = (t < nb) ? bsum[t] : 0;
  sh[t] = v;
  __syncthreads();
  for (int off = 1; off < 256; off <<= 1) {
    int add = (t >= off) ? sh[t - off] : 0;
    __syncthreads();
    sh[t] += add;
    __syncthreads();
  }
  if (t < nb) bsum[t] = sh[t] - v;
  if (t == 255) row_ptr[N] = sh[255];
}

__global__ __launch_bounds__(256) void k_scan3(const int* __restrict__ deg,
                                               const int* __restrict__ boff,
                                               int* __restrict__ row_ptr, int N) {
  __shared__ int sh[256];
  int t = threadIdx.x;
  int base = blockIdx.x * 2048 + t * 8;
  int d[8];
  int s = 0;
#pragma unroll
  for (int j = 0; j < 8; ++j) {
    int i = base + j;
    d[j] = (i < N) ? deg[i] : 0;
    s += d[j];
  }
  sh[t] = s;
  __syncthreads();
  for (int off = 1; off < 256; off <<= 1) {
    int add = (t >= off) ? sh[t - off] : 0;
    __syncthreads();
    sh[t] += add;
    __syncthreads();
  }
  int run = boff[blockIdx.x] + sh[t] - s;
#pragma unroll
  for (int j = 0; j < 8; ++j) {
    int i = base + j;
    if (i < N) {
      row_ptr[i] = run;
      run += d[j];
    }
  }
}

__global__ __launch_bounds__(256) void k_binA(const int* __restrict__ ei,
                                              const int* __restrict__ row_ptr,
                                              int* __restrict__ bktcur,
                                              int* __restrict__ staged,
                                              int E, int NB) {
  __shared__ int hist[512];
  __shared__ int lbase[512];
  int tid = threadIdx.x;
  hist[tid] = 0; hist[tid + 256] = 0;
  __syncthreads();
  int e0 = blockIdx.x * 4096;
#pragma unroll
  for (int j = 0; j < 16; ++j) {
    int e = e0 + j * 256 + tid;
    if (e < E) atomicAdd(&hist[ei[E + e] >> 8], 1);
  }
  __syncthreads();
  for (int t = tid; t < NB; t += 256) {
    int cgot = hist[t];
    if (cgot > 0) lbase[t] = row_ptr[t << 8] + atomicAdd(&bktcur[t], cgot);
    hist[t] = 0;
  }
  __syncthreads();
#pragma unroll
  for (int j = 0; j < 16; ++j) {
    int e = e0 + j * 256 + tid;
    if (e < E) {
      int d = ei[E + e];
      int b = d >> 8;
      int loc = atomicAdd(&hist[b], 1);
      staged[lbase[b] + loc] = (ei[e] << 8) | (d & 255);
    }
  }
}

__global__ __launch_bounds__(256) void k_binB(const int* __restrict__ row_ptr,
                                              const int* __restrict__ staged,
                                              int* __restrict__ csr, int N) {
  __shared__ int lcur[256];
  int b = blockIdx.x;
  int node0 = b << 8;
  int tid = threadIdx.x;
  int nend = min(node0 + 256, N);
  lcur[tid] = (node0 + tid < N) ? row_ptr[node0 + tid] : 0;
  __syncthreads();
  int s0 = row_ptr[node0];
  int s1 = row_ptr[nend];
  for (int j = s0 + tid; j < s1; j += 256) {
    int rec = staged[j];
    int pos = atomicAdd(&lcur[rec & 255], 1);
    csr[pos] = rec >> 8;
  }
}

// ---------------- aggregation (bf16) ----------------
__device__ __forceinline__ void acc8(float* a, uint4 v) {
  a[0] += bf2f((unsigned short)v.x); a[1] += bf2f((unsigned short)(v.x >> 16));
  a[2] += bf2f((unsigned short)v.y); a[3] += bf2f((unsigned short)(v.y >> 16));
  a[4] += bf2f((unsigned short)v.z); a[5] += bf2f((unsigned short)(v.z >> 16));
  a[6] += bf2f((unsigned short)v.w); a[7] += bf2f((unsigned short)(v.w >> 16));
}

__global__ __launch_bounds__(256) void k_aggregate(const unsigned short* __restrict__ h,
                                                   const int* __restrict__ row_ptr,
                                                   const int* __restrict__ csr,
                                                   unsigned short* __restrict__ z,
                                                   int N) {
  int n = blockIdx.x * 16 + (threadIdx.x >> 4);
  if (n >= N) return;
  int lane = threadIdx.x & 15;
  const uint4* __restrict__ hp = (const uint4*)h;
  float a[8];
  {
    uint4 u = hp[(size_t)n * 16 + lane];
    a[0] = bf2f((unsigned short)u.x); a[1] = bf2f((unsigned short)(u.x >> 16));
    a[2] = bf2f((unsigned short)u.y); a[3] = bf2f((unsigned short)(u.y >> 16));
    a[4] = bf2f((unsigned short)u.z); a[5] = bf2f((unsigned short)(u.z >> 16));
    a[6] = bf2f((unsigned short)u.w); a[7] = bf2f((unsigned short)(u.w >> 16));
  }
  int beg = row_ptr[n], end = row_ptr[n + 1];
  int j = beg;
  for (; j + 4 <= end; j += 4) {
    int s0 = csr[j], s1 = csr[j + 1], s2 = csr[j + 2], s3 = csr[j + 3];
    uint4 v0 = hp[(size_t)s0 * 16 + lane];
    uint4 v1 = hp[(size_t)s1 * 16 + lane];
    uint4 v2 = hp[(size_t)s2 * 16 + lane];
    uint4 v3 = hp[(size_t)s3 * 16 + lane];
    acc8(a, v0); acc8(a, v1); acc8(a, v2); acc8(a, v3);
  }
  for (; j < end; ++j) {
    uint4 v = hp[(size_t)csr[j] * 16 + lane];
    acc8(a, v);
  }
  u32x4 o;
  o.x = (unsigned int)f2bf(a[0]) | ((unsigned int)f2bf(a[1]) << 16);
  o.y = (unsigned int)f2bf(a[2]) | ((unsigned int)f2bf(a[3]) << 16);
  o.z = (unsigned int)f2bf(a[4]) | ((unsigned int)f2bf(a[5]) << 16);
  o.w = (unsigned int)f2bf(a[6]) | ((unsigned int)f2bf(a[7]) << 16);
  __builtin_nontemporal_store(o, (u32x4*)z + (size_t)n * 16 + lane);
}

// ---------------- MFMA GEMM: 64x128 tile, BK=64, global_load_lds staging -----
// LDS layout: linear rows of 64 shorts (128 B); 16B slot XOR-swizzled:
//   LDS[row*64 + (g ^ (row&7))*8] holds global granule (row, g).
// B (and A when no kscale) staged via global_load_lds w/ swizzled source;
// A with kscale staged via registers writing the same layout.
__global__ __launch_bounds__(256) void k_gemm_mfma(
    const unsigned short* __restrict__ A, const unsigned short* __restrict__ Wt,
    const float* __restrict__ bias, const float* __restrict__ kscale,
    const float* __restrict__ kshift, void* __restrict__ Cout, int outBf16,
    float* __restrict__ pS, float* __restrict__ pQ, int mblocks,
    int M, int K, int Nc) {
  __shared__ unsigned short As[64 * 64];    // 8 KB
  __shared__ unsigned short Bs[128 * 64];   // 16 KB
  __shared__ float redS[128];
  __shared__ float redQ[128];
  __shared__ float ksc[256];
  __shared__ float ksh[256];

  int tid = threadIdx.x;
  int lane = tid & 63;
  int wid = tid >> 6;
  int wrow = (wid & 1) * 32;
  int wcol = (wid >> 1) * 64;
  int bm = blockIdx.x * 64;
  int bn = blockIdx.y * 128;
  int lrow = lane & 15;
  int lkg = lane >> 4;
  int lsl = lrow & 7;               // row&7 for fragment reads
  int crow = lane >> 3;             // chunk-local row 0..7
  int cg = (lane & 7) ^ crow;       // swizzled source granule

  if (tid < 128) { redS[tid] = 0.f; redQ[tid] = 0.f; }
  if (kscale) {
    for (int k = tid; k < K; k += 256) { ksc[k] = kscale[k]; ksh[k] = kshift[k]; }
  }

  f32x4 acc[2][4];
#pragma unroll
  for (int r = 0; r < 2; ++r)
#pragma unroll
    for (int c = 0; c < 4; ++c) acc[r][c] = (f32x4){0.f, 0.f, 0.f, 0.f};

  for (int kt = 0; kt < K; kt += 64) {
    __syncthreads();
    // ---- stage B: 16 chunks of 1024B via global_load_lds ----
#pragma unroll
    for (int c = 0; c < 4; ++c) {
      int ch = wid * 4 + c;
      int row = ch * 8 + crow;
      const unsigned short* gp = Wt + (size_t)(bn + row) * K + kt + cg * 8;
      gload_lds16(gp, Bs + ch * 512);
    }
    // ---- stage A ----
    if (kscale) {
      // register path (BN+ReLU transform), swizzled ds_write
#pragma unroll
      for (int it = 0; it < 2; ++it) {
        int ga = it * 256 + tid;
        int row = ga >> 3, g = ga & 7;
        bf16x8 av = (bf16x8){0, 0, 0, 0, 0, 0, 0, 0};
        int grow = bm + row;
        if (grow < M) av = *(const bf16x8*)(A + (size_t)grow * K + kt + g * 8);
        int k0 = kt + g * 8;
#pragma unroll
        for (int j = 0; j < 8; ++j) {
          float f = bf2f((unsigned short)av[j]);
          f = fmaxf(fmaf(f, ksc[k0 + j], ksh[k0 + j]), 0.f);
          av[j] = (short)f2bf(f);
        }
        *(bf16x8*)(As + row * 64 + ((g ^ (row & 7)) * 8)) = av;
      }
    } else {
      // DMA path: 8 chunks; tail rows read in-workspace garbage (discarded)
#pragma unroll
      for (int c = 0; c < 2; ++c) {
        int ch = wid * 2 + c;
        int row = ch * 8 + crow;
        const unsigned short* gp = A + (size_t)(bm + row) * K + kt + cg * 8;
        gload_lds16(gp, As + ch * 512);
      }
    }
    __syncthreads();
    // ---- compute ----
#pragma unroll
    for (int ks = 0; ks < 2; ++ks) {
      int goff = ks * 4 + lkg;
      int slot = (goff ^ lsl) * 8;
      bf16x8 af[2], bfr[4];
#pragma unroll
      for (int rf = 0; rf < 2; ++rf)
        af[rf] = *(const bf16x8*)(As + (wrow + rf * 16 + lrow) * 64 + slot);
#pragma unroll
      for (int cf = 0; cf < 4; ++cf)
        bfr[cf] = *(const bf16x8*)(Bs + (wcol + cf * 16 + lrow) * 64 + slot);
#pragma unroll
      for (int rf = 0; rf < 2; ++rf)
#pragma unroll
        for (int cf = 0; cf < 4; ++cf)
          acc[rf][cf] = __builtin_amdgcn_mfma_f32_16x16x32_bf16(
              af[rf], bfr[cf], acc[rf][cf], 0, 0, 0);
    }
  }

#pragma unroll
  for (int cf = 0; cf < 4; ++cf) {
    int lcol = wcol + cf * 16 + lrow;
    float bb = bias[bn + lcol];
    float s = 0.f, q = 0.f;
#pragma unroll
    for (int rf = 0; rf < 2; ++rf) {
#pragma unroll
      for (int j = 0; j < 4; ++j) {
        float v = acc[rf][cf][j] + bb;
        acc[rf][cf][j] = v;
        int grow = bm + wrow + rf * 16 + lkg * 4 + j;
        if (grow < M) { s += v; q += v * v; }
      }
    }
    s += __shfl_xor(s, 16); s += __shfl_xor(s, 32);
    q += __shfl_xor(q, 16); q += __shfl_xor(q, 32);
    if (lane < 16) {
      atomicAdd(&redS[lcol], s);
      atomicAdd(&redQ[lcol], q);
    }
  }

#pragma unroll
  for (int cf = 0; cf < 4; ++cf) {
    int col = bn + wcol + cf * 16 + lrow;
#pragma unroll
    for (int rf = 0; rf < 2; ++rf) {
#pragma unroll
      for (int j = 0; j < 4; ++j) {
        int grow = bm + wrow + rf * 16 + lkg * 4 + j;
        if (grow < M) {
          float v = acc[rf][cf][j];
          if (outBf16)
            ((unsigned short*)Cout)[(size_t)grow * Nc + col] = f2bf(v);
          else
            ((float*)Cout)[(size_t)grow * Nc + col] = v;
        }
      }
    }
  }
  __syncthreads();
  if (tid < 128) {
    size_t off = (size_t)(bn + tid) * mblocks + blockIdx.x;
    pS[off] = redS[tid];
    pQ[off] = redQ[tid];
  }
}

__global__ __launch_bounds__(256) void k_bnfin2(const float* __restrict__ pS,
                                                const float* __restrict__ pQ,
                                                const float* __restrict__ g,
                                                const float* __restrict__ b,
                                                float* __restrict__ scale,
                                                float* __restrict__ shift,
                                                int mblocks, float invM) {
  __shared__ float shS[256], shQ[256];
  int c = blockIdx.x;
  int t = threadIdx.x;
  const float* rs = pS + (size_t)c * mblocks;
  const float* rq = pQ + (size_t)c * mblocks;
  float s = 0.f, q = 0.f;
  for (int j = t; j < mblocks; j += 256) { s += rs[j]; q += rq[j]; }
  shS[t] = s; shQ[t] = q;
  __syncthreads();
  for (int off = 128; off > 0; off >>= 1) {
    if (t < off) { shS[t] += shS[t + off]; shQ[t] += shQ[t + off]; }
    __syncthreads();
  }
  if (t == 0) {
    float mean = shS[0] * invM;
    float var = shQ[0] * invM - mean * mean;
    float inv = rsqrtf(var + BN_EPS);
    float sc = g[c] * inv;
    scale[c] = sc;
    shift[c] = fmaf(-mean, sc, b[c]);
  }
}

// ---------------- GEMM 64x64 f32 (vn-MLP, 512 rows) ----------------
__global__ __launch_bounds__(256) void k_gemm(const float* __restrict__ A,
                                              const float* __restrict__ B,
                                              const float* __restrict__ bias,
                                              const float* __restrict__ kscale,
                                              const float* __restrict__ kshift,
                                              float* __restrict__ C,
                                              int M, int K, int Nc) {
  __shared__ float As[16][65];
  __shared__ float Bs[16][65];
  int tid = threadIdx.x;
  int bm = blockIdx.x * 64;
  int bn = blockIdx.y * 64;
  int trow = (tid >> 4) << 2;
  int tcol = (tid & 15) << 2;
  float acc[4][4] = {};

  int arow = tid >> 2;
  int ak = (tid & 3) << 2;
  int bt4 = tid << 2;
  int bk = bt4 >> 6;
  int bcol = bt4 & 63;

  for (int kt = 0; kt < K; kt += 16) {
    float4 av = make_float4(0.f, 0.f, 0.f, 0.f);
    int grow = bm + arow;
    if (grow < M) av = *(const float4*)(A + (size_t)grow * K + kt + ak);
    if (kscale) {
      int k0 = kt + ak;
      av.x = fmaxf(fmaf(av.x, kscale[k0 + 0], kshift[k0 + 0]), 0.f);
      av.y = fmaxf(fmaf(av.y, kscale[k0 + 1], kshift[k0 + 1]), 0.f);
      av.z = fmaxf(fmaf(av.z, kscale[k0 + 2], kshift[k0 + 2]), 0.f);
      av.w = fmaxf(fmaf(av.w, kscale[k0 + 3], kshift[k0 + 3]), 0.f);
    }
    float4 bv = *(const float4*)(B + (size_t)(kt + bk) * Nc + bn + bcol);
    __syncthreads();
    As[ak + 0][arow] = av.x;
    As[ak + 1][arow] = av.y;
    As[ak + 2][arow] = av.z;
    As[ak + 3][arow] = av.w;
    Bs[bk][bcol + 0] = bv.x;
    Bs[bk][bcol + 1] = bv.y;
    Bs[bk][bcol + 2] = bv.z;
    Bs[bk][bcol + 3] = bv.w;
    __syncthreads();
#pragma unroll
    for (int k = 0; k < 16; ++k) {
      float a0 = As[k][trow + 0], a1 = As[k][trow + 1];
      float a2 = As[k][trow + 2], a3 = As[k][trow + 3];
      float b0 = Bs[k][tcol + 0], b1 = Bs[k][tcol + 1];
      float b2 = Bs[k][tcol + 2], b3 = Bs[k][tcol + 3];
      acc[0][0] = fmaf(a0, b0, acc[0][0]); acc[0][1] = fmaf(a0, b1, acc[0][1]);
      acc[0][2] = fmaf(a0, b2, acc[0][2]); acc[0][3] = fmaf(a0, b3, acc[0][3]);
      acc[1][0] = fmaf(a1, b0, acc[1][0]); acc[1][1] = fmaf(a1, b1, acc[1][1]);
      acc[1][2] = fmaf(a1, b2, acc[1][2]); acc[1][3] = fmaf(a1, b3, acc[1][3]);
      acc[2][0] = fmaf(a2, b0, acc[2][0]); acc[2][1] = fmaf(a2, b1, acc[2][1]);
      acc[2][2] = fmaf(a2, b2, acc[2][2]); acc[2][3] = fmaf(a2, b3, acc[2][3]);
      acc[3][0] = fmaf(a3, b0, acc[3][0]); acc[3][1] = fmaf(a3, b1, acc[3][1]);
      acc[3][2] = fmaf(a3, b2, acc[3][2]); acc[3][3] = fmaf(a3, b3, acc[3][3]);
    }
  }
#pragma unroll
  for (int r = 0; r < 4; ++r) {
    int grow = bm + trow + r;
    if (grow < M) {
      float4 o;
      o.x = acc[r][0] + bias[bn + tcol + 0];
      o.y = acc[r][1] + bias[bn + tcol + 1];
      o.z = acc[r][2] + bias[bn + tcol + 2];
      o.w = acc[r][3] + bias[bn + tcol + 3];
      *(float4*)(C + (size_t)grow * Nc + bn + tcol) = o;
    }
  }
}

// ---------------- BN stats / finalize (vn-MLP path) ----------------

__global__ void k_colstats(const float* __restrict__ Y, int M, int C, int stripe,
                           float* __restrict__ sum, float* __restrict__ sumsq) {
  int c = threadIdx.x;
  int r0 = blockIdx.x * stripe;
  int r1 = min(r0 + stripe, M);
  float s = 0.f, ss = 0.f;
  for (int r = r0; r < r1; ++r) {
    float v = Y[(size_t)r * C + c];
    s += v; ss += v * v;
  }
  atomicAdd(&sum[c], s);
  atomicAdd(&sumsq[c], ss);
}

__global__ void k_bnfin(const float* __restrict__ sum, const float* __restrict__ sumsq,
                        const float* __restrict__ g, const float* __restrict__ b,
                        float* __restrict__ scale, float* __restrict__ shift,
                        int C, float invM) {
  int c = threadIdx.x;
  if (c >= C) return;
  float mean = sum[c] * invM;
  float var = sumsq[c] * invM - mean * mean;
  float inv = rsqrtf(var + BN_EPS);
  float sc = g[c] * inv;
  scale[c] = sc;
  shift[c] = fmaf(-mean, sc, b[c]);
}

// ---------------- pooling / readout / small ops ----------------

__global__ __launch_bounds__(256) void k_pool2(const float* __restrict__ X,
                                               const int* __restrict__ batch,
                                               float* __restrict__ pooled,
                                               float* __restrict__ counts, int N) {
  int c = threadIdx.x & 127;
  int half = threadIdx.x >> 7;
  int base = blockIdx.x * 128 + half * 64;
  if (base >= N) return;
  int lim = min(64, N - base);
  int g = batch[base];
  float acc = 0.f, cnt = 0.f;
  for (int r = 0; r < lim; ++r) {
    int bg = batch[base + r];
    if (bg != g) {
      atomicAdd(&pooled[(size_t)g * HDIM + c], acc);
      if (c == 0 && counts) atomicAdd(&counts[g], cnt);
      acc = 0.f; cnt = 0.f; g = bg;
    }
    acc += X[(size_t)(base + r) * HDIM + c];
    cnt += 1.f;
  }
  atomicAdd(&pooled[(size_t)g * HDIM + c], acc);
  if (c == 0 && counts) atomicAdd(&counts[g], cnt);
}

__global__ __launch_bounds__(256) void k_pool2_b(const unsigned short* __restrict__ X,
                                                 const int* __restrict__ batch,
                                                 float* __restrict__ pooled, int N) {
  int c = threadIdx.x & 127;
  int half = threadIdx.x >> 7;
  int base = blockIdx.x * 128 + half * 64;
  if (base >= N) return;
  int lim = min(64, N - base);
  int g = batch[base];
  float acc = 0.f;
  for (int r = 0; r < lim; ++r) {
    int bg = batch[base + r];
    if (bg != g) {
      atomicAdd(&pooled[(size_t)g * HDIM + c], acc);
      acc = 0.f; g = bg;
    }
    acc += bf2f(X[(size_t)(base + r) * HDIM + c]);
  }
  atomicAdd(&pooled[(size_t)g * HDIM + c], acc);
}

__global__ __launch_bounds__(256) void k_add(const float* __restrict__ a,
                                             const float* __restrict__ b,
                                             float* __restrict__ o, int n) {
  int idx = blockIdx.x * 256 + threadIdx.x;
  if (idx < n) o[idx] = a[idx] + b[idx];
}

__global__ __launch_bounds__(256) void k_readout(const float* __restrict__ pooled,
                                                 const float* __restrict__ counts,
                                                 float* __restrict__ out, int n) {
  int idx = blockIdx.x * 256 + threadIdx.x;
  if (idx >= n) return;
  int g = idx >> 7;
  out[idx] = pooled[idx] / fmaxf(counts[g], 1.0f);
}

// ---------------- launch ----------------

extern "C" void kernel_launch(void* const* d_in, const int* in_sizes, int n_in,
                              void* d_out, int out_size, void* d_ws, size_t ws_size,
                              hipStream_t stream) {
  const float* x       = (const float*)d_in[0];
  const int*   ei      = (const int*)d_in[1];
  const int*   batch   = (const int*)d_in[2];
  const float* conv_w1 = (const float*)d_in[4];
  const float* conv_b1 = (const float*)d_in[5];
  const float* conv_bng = (const float*)d_in[6];
  const float* conv_bnb = (const float*)d_in[7];
  const float* conv_w2 = (const float*)d_in[8];
  const float* conv_b2 = (const float*)d_in[9];
  const float* bn_g    = (const float*)d_in[10];
  const float* bn_b    = (const float*)d_in[11];
  const float* vn_emb  = (const float*)d_in[12];
  const float* vw1     = (const float*)d_in[13];
  const float* vb1     = (const float*)d_in[14];
  const float* vbn1g   = (const float*)d_in[15];
  const float* vbn1b   = (const float*)d_in[16];
  const float* vw2     = (const float*)d_in[17];
  const float* vb2     = (const float*)d_in[18];
  const float* vbn2g   = (const float*)d_in[19];
  const float* vbn2b   = (const float*)d_in[20];

  const int N = in_sizes[2];
  const int E = in_sizes[1] / 2;
  const int L = 3;

  const size_t NH  = (size_t)N * HDIM;
  const size_t NH2 = (size_t)N * H2DIM;

  float*          y2   = (float*)d_ws;
  unsigned short* h_b  = (unsigned short*)d_ws;
  unsigned short* z_b  = h_b + NH;            // also y2b (bf16 y2, layers 0/1)
  unsigned short* y1_b = z_b + NH;
  unsigned short* wt1b = y1_b + NH2;
  unsigned short* wt2b = wt1b + (size_t)3 * H2DIM * HDIM;
  float* sum1   = (float*)(wt2b + (size_t)3 * HDIM * H2DIM);
  float* ss1    = sum1 + H2DIM;
  float* sum2   = ss1 + H2DIM;
  float* ss2    = sum2 + HDIM;
  float* scale1 = ss2 + HDIM;
  float* shift1 = scale1 + H2DIM;
  float* scale2 = shift1 + H2DIM;
  float* shift2 = scale2 + HDIM;
  float* vf     = shift2 + HDIM;
  float* pooled = vf + (size_t)GNUM * HDIM;
  float* vin    = pooled + (size_t)GNUM * HDIM;
  float* v1     = vin + (size_t)GNUM * HDIM;
  float* counts = v1 + (size_t)GNUM * H2DIM;
  int*   cursor = (int*)(counts + GNUM);
  int*   bktcur = cursor + N;
  int*   row_ptr = bktcur + 512;
  int*   csr    = row_ptr + N + 1;
  int*   staged = csr + E;
  int*   bsum   = staged + E;
  unsigned short* hb2 = (unsigned short*)(bsum + 256);
  unsigned short* fb2 = hb2 + NH;

  const int mblocks = (N + 63) / 64;
  float* pS = (float*)staged;
  float* pQ = pS + (size_t)256 * mblocks;

  float* out_feats = (float*)d_out;
  float* out_read  = out_feats + NH;
  float* out_vf    = out_read + (size_t)GNUM * HDIM;

  dim3 blk(256);
  const int gridNH4 = (int)((NH / 4 + 255) / 256);
  const int gridE = (E + 255) / 256;
  const int nb = (N + 2047) / 2048;
  const int NB = (N + 255) >> 8;

  // ---- CSR build ----
  hipMemsetAsync(cursor, 0, (size_t)(N + 512) * sizeof(int), stream);
  k_hist<<<gridE, blk, 0, stream>>>(ei, cursor, E);
  k_scan1<<<nb, blk, 0, stream>>>(cursor, bsum, N);
  k_scan2<<<1, blk, 0, stream>>>(bsum, nb, row_ptr, N);
  k_scan3<<<nb, blk, 0, stream>>>(cursor, bsum, row_ptr, N);
  k_binA<<<(E + 4095) / 4096, blk, 0, stream>>>(ei, row_ptr, bktcur, staged, E, NB);
  k_binB<<<NB, blk, 0, stream>>>(row_ptr, staged, csr, N);

  // ---- weight conversion ----
  k_convw_all<<<(2 * 3 * HDIM * H2DIM + 255) / 256, blk, 0, stream>>>(
      conv_w1, conv_w2, wt1b, wt2b);

  k_init_vf<<<(GNUM * HDIM + 255) / 256, blk, 0, stream>>>(vn_emb, vf);

  for (int i = 0; i < L; ++i) {
    if (i == 0)
      k_h_init<<<gridNH4, blk, 0, stream>>>(x, h_b, N);
    else if (i == 2)
      k_h_init_b<<<gridNH4, blk, 0, stream>>>(fb2, vf, batch, h_b, N);
    const unsigned short* hcur = (i == 1) ? hb2 : h_b;

    k_aggregate<<<(N + 15) / 16, blk, 0, stream>>>(hcur, row_ptr, csr, z_b, N);

    // GEMM1: y1_b(bf16) = z_b @ W1[i] + b1[i]
    k_gemm_mfma<<<dim3(mblocks, H2DIM / 128), blk, 0, stream>>>(
        z_b, wt1b + (size_t)i * H2DIM * HDIM, conv_b1 + (size_t)i * H2DIM,
        nullptr, nullptr, y1_b, 1, pS, pQ, mblocks, N, HDIM, H2DIM);
    k_bnfin2<<<H2DIM, blk, 0, stream>>>(pS, pQ, conv_bng + (size_t)i * H2DIM,
                                        conv_bnb + (size_t)i * H2DIM,
                                        scale1, shift1, mblocks, 1.0f / N);

    // GEMM2: y2 = relu(bn(y1)) @ W2[i] + b2[i]; bf16 output into z_b for i<2
    int outBf = (i < 2) ? 1 : 0;
    void* y2dst = (i < 2) ? (void*)z_b : (void*)y2;
    k_gemm_mfma<<<dim3(mblocks, HDIM / 128), blk, 0, stream>>>(
        y1_b, wt2b + (size_t)i * HDIM * H2DIM, conv_b2 + (size_t)i * HDIM,
        scale1, shift1, y2dst, outBf, pS, pQ, mblocks, N, H2DIM, HDIM);
    k_bnfin2<<<HDIM, blk, 0, stream>>>(pS, pQ, bn_g + (size_t)i * HDIM,
                                       bn_b + (size_t)i * HDIM,
                                       scale2, shift2, mblocks, 1.0f / N);

    if (i == 0) {
      k_bnfuse_b<<<gridNH4, blk, 0, stream>>>(z_b, scale2, shift2, vf, batch,
                                              hb2, N);
    } else if (i == 1) {
      k_bnapply_b1<<<gridNH4, blk, 0, stream>>>(z_b, scale2, shift2, fb2, N);
    } else {
      k_bnapply<<<gridNH4, blk, 0, stream>>>(y2, scale2, shift2, out_feats,
                                             (long long)(NH / 4), HDIM / 4, 0);
    }

    if (i == 1) {
      hipMemsetAsync(pooled, 0, (size_t)GNUM * HDIM * sizeof(float), stream);
      k_pool2_b<<<(N + 127) / 128, blk, 0, stream>>>(fb2, batch, pooled, N);
      k_add<<<(GNUM * HDIM + 255) / 256, blk, 0, stream>>>(pooled, vf, vin,
                                                           GNUM * HDIM);

      hipMemsetAsync(sum1, 0, (size_t)(2 * H2DIM + 2 * HDIM) * sizeof(float), stream);
      k_gemm<<<dim3(GNUM / 64, H2DIM / 64), blk, 0, stream>>>(
          vin, vw1, vb1, nullptr, nullptr, v1, GNUM, HDIM, H2DIM);
      k_colstats<<<(GNUM + 127) / 128, H2DIM, 0, stream>>>(v1, GNUM, H2DIM, 128,
                                                           sum1, ss1);
      k_bnfin<<<1, H2DIM, 0, stream>>>(sum1, ss1, vbn1g, vbn1b, scale1, shift1,
                                       H2DIM, 1.0f / GNUM);

      k_gemm<<<dim3(GNUM / 64, HDIM / 64), blk, 0, stream>>>(
          v1, vw2, vb2, scale1, shift1, vin, GNUM, H2DIM, HDIM);
      k_colstats<<<(GNUM + 127) / 128, HDIM, 0, stream>>>(vin, GNUM, HDIM, 128,
                                                          sum2, ss2);
      k_bnfin<<<1, HDIM, 0, stream>>>(sum2, ss2, vbn2g, vbn2b, scale2, shift2,
                                      HDIM, 1.0f / GNUM);
      k_bnapply<<<(GNUM * HDIM / 4 + 255) / 256, blk, 0, stream>>>(
          vin, scale2, shift2, vf, (long long)(GNUM * HDIM / 4), HDIM / 4, 1);
    }
  }

  hipMemsetAsync(pooled, 0, (size_t)GNUM * HDIM * sizeof(float), stream);
  hipMemsetAsync(counts, 0, (size_t)GNUM * sizeof(float), stream);
  k_pool2<<<(N + 127) / 128, blk, 0, stream>>>(out_feats, batch, pooled, counts, N);
  k_readout<<<(GNUM * HDIM + 255) / 256, blk, 0, stream>>>(pooled, counts, out_read,
                                                           GNUM * HDIM);
  hipMemcpyAsync(out_vf, vf, (size_t)GNUM * HDIM * sizeof(float),
                 hipMemcpyDeviceToDevice, stream);
}